// Round 16
// baseline (380.623 us; speedup 1.0000x reference)
//
#include <hip/hip_runtime.h>
#include <hip/hip_cooperative_groups.h>

namespace cg = cooperative_groups;

#define HID 64

// int16 quantization scales
#define QS1   4096.0f   // hs1 range +-8
#define QINV1 (1.0f/4096.0f)
#define QH1   2048.0f   // h1 range +-16
#define QS2   2048.0f   // hs2 range +-16
#define QINV2 (1.0f/2048.0f)

#define NBLKC 512       // cooperative build grid (fixed)
#define BKCAP 4096

// ================= fused atomic-free CSR build (one cooperative kernel) =================
// Buckets of 256 dst nodes (nb=391). hist layout [bucket][block]: idx = b*512 + blk.
// Scan chunk c = bucket row c (512 entries) -> block offsets indexed directly by bucket.
// sorted packed: (src << 8) | (dst & 255).
__global__ void __launch_bounds__(256) build_fused_kernel(
    const int4* __restrict__ src4, const int4* __restrict__ dst4,
    int* __restrict__ hist, int* __restrict__ tmp, int* __restrict__ bsum, int* __restrict__ boff,
    int* __restrict__ sorted, int* __restrict__ row_ptr, float* __restrict__ dinv,
    int* __restrict__ col, int n4, int n, int n_edges, int epb4, int nb) {
    cg::grid_group grid = cg::this_grid();
    __shared__ int S[768 + BKCAP];
    const int tid = threadIdx.x, blk = blockIdx.x;
    const int beg4 = blk * epb4;
    const int end4 = min(n4, beg4 + epb4);

    // ---- P1: per-block LDS histogram of dst buckets ----
    S[tid] = 0; S[tid + 256] = 0;
    __syncthreads();
    for (int j = beg4 + tid; j < end4; j += 256) {
        int4 d = dst4[j];
        atomicAdd(&S[d.x >> 8], 1);
        atomicAdd(&S[d.y >> 8], 1);
        atomicAdd(&S[d.z >> 8], 1);
        atomicAdd(&S[d.w >> 8], 1);
    }
    __syncthreads();
    for (int b = tid; b < nb; b += 256) hist[b * NBLKC + blk] = S[b];
    grid.sync();

    // ---- P2a: scan each bucket row (512 entries, 2/thread) ----
    if (blk < nb) {
        int i0 = blk * NBLKC + tid * 2;
        int a = hist[i0], bb = hist[i0 + 1];
        int v = a + bb;
        S[tid] = v;
        __syncthreads();
#pragma unroll
        for (int off = 1; off < 256; off <<= 1) {
            int t = (tid >= off) ? S[tid - off] : 0;
            __syncthreads();
            S[tid] += t;
            __syncthreads();
        }
        int excl = S[tid] - v;
        tmp[i0] = excl;
        tmp[i0 + 1] = excl + a;
        if (tid == 255) bsum[blk] = S[255];
    }
    grid.sync();

    // ---- P2b: scan the nb bucket totals (block 0) ----
    if (blk == 0) {
        int i0 = tid * 2;
        int a = (i0 < nb) ? bsum[i0] : 0;
        int bb = (i0 + 1 < nb) ? bsum[i0 + 1] : 0;
        int v = a + bb;
        S[tid] = v;
        __syncthreads();
#pragma unroll
        for (int off = 1; off < 256; off <<= 1) {
            int t = (tid >= off) ? S[tid - off] : 0;
            __syncthreads();
            S[tid] += t;
            __syncthreads();
        }
        int excl = S[tid] - v;
        if (i0 < nb) boff[i0] = excl;
        if (i0 + 1 < nb) boff[i0 + 1] = excl + a;
    }
    grid.sync();

    // ---- P3: partition edges into bucket regions (LDS cursors) ----
    for (int b = tid; b < nb; b += 256) S[b] = tmp[b * NBLKC + blk] + boff[b];
    __syncthreads();
    for (int j = beg4 + tid; j < end4; j += 256) {
        int4 d = dst4[j];
        int4 s = src4[j];
        int p0 = atomicAdd(&S[d.x >> 8], 1);
        int p1 = atomicAdd(&S[d.y >> 8], 1);
        int p2 = atomicAdd(&S[d.z >> 8], 1);
        int p3 = atomicAdd(&S[d.w >> 8], 1);
        sorted[p0] = (s.x << 8) | (d.x & 255);
        sorted[p1] = (s.y << 8) | (d.y & 255);
        sorted[p2] = (s.z << 8) | (d.z & 255);
        sorted[p3] = (s.w << 8) | (d.w & 255);
    }
    grid.sync();

    // ---- P4: per-bucket packed CSR + dinv ----
    if (blk < nb) {
        int* cnt = S;
        int* sc = S + 256;
        int* cur = S + 512;
        int* ecache = S + 768;
        const int base = tmp[blk * NBLKC] + boff[blk];
        const int end = (blk == nb - 1) ? n_edges : (tmp[(blk + 1) * NBLKC] + boff[blk + 1]);
        const int m = end - base;
        const bool fits = (m <= BKCAP);

        cnt[tid] = 0;
        __syncthreads();
        if (fits) {
            for (int e = tid; e < m; e += 256) {
                int v = sorted[base + e];
                ecache[e] = v;
                atomicAdd(&cnt[v & 255], 1);
            }
        } else {
            for (int e = base + tid; e < end; e += 256)
                atomicAdd(&cnt[sorted[e] & 255], 1);
        }
        __syncthreads();

        sc[tid] = cnt[tid];
        __syncthreads();
#pragma unroll
        for (int off = 1; off < 256; off <<= 1) {
            int t = (tid >= off) ? sc[tid - off] : 0;
            __syncthreads();
            sc[tid] += t;
            __syncthreads();
        }
        int ex = sc[tid] - cnt[tid];
        cur[tid] = ex;

        int node = blk * 256 + tid;
        if (node < n) {
            row_ptr[node] = base + ex;
            dinv[node] = rsqrtf((float)(cnt[tid] + 1));   // +1 = self-loop
        }
        if (blk == nb - 1 && tid == 0) row_ptr[n] = n_edges;
        __syncthreads();

        if (fits) {
            for (int e = tid; e < m; e += 256) {
                int v = ecache[e];
                int lp = atomicAdd(&cur[v & 255], 1);
                col[base + lp] = v >> 8;
            }
        } else {
            for (int e = base + tid; e < end; e += 256) {
                int v = sorted[e];
                int lp = atomicAdd(&cur[v & 255], 1);
                col[base + lp] = v >> 8;
            }
        }
    }
}

// ---------------- gemm1 (fp32 in, int16 out): hsq = q(dinv * X@W^T) ----------------
template<int K>
__global__ void __launch_bounds__(256) gemm_tile_kernel(
    const float* __restrict__ X, const float* __restrict__ W,
    const float* __restrict__ dinv, short* __restrict__ outq, float qs, int n) {
    constexpr int BK = 32;
    constexpr int NKB = K / BK;
    __shared__ float As[BK][132];
    __shared__ float Bs[BK][68];

    const int t = threadIdx.x;
    const int mbase = blockIdx.x * 128;
    const int tc = t & 15;
    const int tm = t >> 4;
    const int lr = t >> 3;
    const int k4 = (t & 7) * 4;

    float acc[8][4] = {};

    for (int kb = 0; kb < NKB; ++kb) {
        __syncthreads();
#pragma unroll
        for (int h = 0; h < 4; ++h) {
            int m = lr + h * 32;
            int node = mbase + m;
            float4 v = make_float4(0.f, 0.f, 0.f, 0.f);
            if (node < n)
                v = *reinterpret_cast<const float4*>(X + (size_t)node * K + kb * BK + k4);
            As[k4 + 0][m] = v.x; As[k4 + 1][m] = v.y;
            As[k4 + 2][m] = v.z; As[k4 + 3][m] = v.w;
        }
#pragma unroll
        for (int h = 0; h < 2; ++h) {
            int c = lr + h * 32;
            float4 wv = *reinterpret_cast<const float4*>(W + (size_t)c * K + kb * BK + k4);
            Bs[k4 + 0][c] = wv.x; Bs[k4 + 1][c] = wv.y;
            Bs[k4 + 2][c] = wv.z; Bs[k4 + 3][c] = wv.w;
        }
        __syncthreads();
#pragma unroll
        for (int k = 0; k < BK; ++k) {
            float4 a0 = *reinterpret_cast<const float4*>(&As[k][tm * 8]);
            float4 a1 = *reinterpret_cast<const float4*>(&As[k][tm * 8 + 4]);
            float4 b = *reinterpret_cast<const float4*>(&Bs[k][tc * 4]);
            acc[0][0] += a0.x * b.x; acc[0][1] += a0.x * b.y; acc[0][2] += a0.x * b.z; acc[0][3] += a0.x * b.w;
            acc[1][0] += a0.y * b.x; acc[1][1] += a0.y * b.y; acc[1][2] += a0.y * b.z; acc[1][3] += a0.y * b.w;
            acc[2][0] += a0.z * b.x; acc[2][1] += a0.z * b.y; acc[2][2] += a0.z * b.z; acc[2][3] += a0.z * b.w;
            acc[3][0] += a0.w * b.x; acc[3][1] += a0.w * b.y; acc[3][2] += a0.w * b.z; acc[3][3] += a0.w * b.w;
            acc[4][0] += a1.x * b.x; acc[4][1] += a1.x * b.y; acc[4][2] += a1.x * b.z; acc[4][3] += a1.x * b.w;
            acc[5][0] += a1.y * b.x; acc[5][1] += a1.y * b.y; acc[5][2] += a1.y * b.z; acc[5][3] += a1.y * b.w;
            acc[6][0] += a1.z * b.x; acc[6][1] += a1.z * b.y; acc[6][2] += a1.z * b.z; acc[6][3] += a1.z * b.w;
            acc[7][0] += a1.w * b.x; acc[7][1] += a1.w * b.y; acc[7][2] += a1.w * b.z; acc[7][3] += a1.w * b.w;
        }
    }

#pragma unroll
    for (int i = 0; i < 8; ++i) {
        int node = mbase + tm * 8 + i;
        if (node < n) {
            float s = dinv[node] * qs;
            int q0 = __float2int_rn(fminf(fmaxf(acc[i][0] * s, -32767.f), 32767.f));
            int q1 = __float2int_rn(fminf(fmaxf(acc[i][1] * s, -32767.f), 32767.f));
            int q2 = __float2int_rn(fminf(fmaxf(acc[i][2] * s, -32767.f), 32767.f));
            int q3 = __float2int_rn(fminf(fmaxf(acc[i][3] * s, -32767.f), 32767.f));
            int2 pk;
            pk.x = (q0 & 0xffff) | (q1 << 16);
            pk.y = (q2 & 0xffff) | (q3 << 16);
            *reinterpret_cast<int2*>(outq + (size_t)node * HID + tc * 4) = pk;
        }
    }
}

// ---------------- gemm2 (int16 in, int16 out), K=64: hs2q = q(dinv * h1 @ W2^T) ----------------
__global__ void __launch_bounds__(256) gemm_tile_q_kernel(
    const short* __restrict__ Xq, const float* __restrict__ W,
    const float* __restrict__ dinv, short* __restrict__ outq, float qs, int n) {
    constexpr int K = 64, BK = 32, NKB = 2;
    __shared__ float As[BK][132];
    __shared__ float Bs[BK][68];

    const int t = threadIdx.x;
    const int mbase = blockIdx.x * 128;
    const int tc = t & 15;
    const int tm = t >> 4;
    const int lr = t >> 3;
    const int k4 = (t & 7) * 4;

    float acc[8][4] = {};

    for (int kb = 0; kb < NKB; ++kb) {
        __syncthreads();
#pragma unroll
        for (int h = 0; h < 4; ++h) {
            int m = lr + h * 32;
            int node = mbase + m;
            int2 raw = make_int2(0, 0);
            if (node < n)
                raw = *reinterpret_cast<const int2*>(Xq + (size_t)node * K + kb * BK + k4);
            As[k4 + 0][m] = (float)((raw.x << 16) >> 16);
            As[k4 + 1][m] = (float)(raw.x >> 16);
            As[k4 + 2][m] = (float)((raw.y << 16) >> 16);
            As[k4 + 3][m] = (float)(raw.y >> 16);
        }
#pragma unroll
        for (int h = 0; h < 2; ++h) {
            int c = lr + h * 32;
            float4 wv = *reinterpret_cast<const float4*>(W + (size_t)c * K + kb * BK + k4);
            Bs[k4 + 0][c] = wv.x; Bs[k4 + 1][c] = wv.y;
            Bs[k4 + 2][c] = wv.z; Bs[k4 + 3][c] = wv.w;
        }
        __syncthreads();
#pragma unroll
        for (int k = 0; k < BK; ++k) {
            float4 a0 = *reinterpret_cast<const float4*>(&As[k][tm * 8]);
            float4 a1 = *reinterpret_cast<const float4*>(&As[k][tm * 8 + 4]);
            float4 b = *reinterpret_cast<const float4*>(&Bs[k][tc * 4]);
            acc[0][0] += a0.x * b.x; acc[0][1] += a0.x * b.y; acc[0][2] += a0.x * b.z; acc[0][3] += a0.x * b.w;
            acc[1][0] += a0.y * b.x; acc[1][1] += a0.y * b.y; acc[1][2] += a0.y * b.z; acc[1][3] += a0.y * b.w;
            acc[2][0] += a0.z * b.x; acc[2][1] += a0.z * b.y; acc[2][2] += a0.z * b.z; acc[2][3] += a0.z * b.w;
            acc[3][0] += a0.w * b.x; acc[3][1] += a0.w * b.y; acc[3][2] += a0.w * b.z; acc[3][3] += a0.w * b.w;
            acc[4][0] += a1.x * b.x; acc[4][1] += a1.x * b.y; acc[4][2] += a1.x * b.z; acc[4][3] += a1.x * b.w;
            acc[5][0] += a1.y * b.x; acc[5][1] += a1.y * b.y; acc[5][2] += a1.y * b.z; acc[5][3] += a1.y * b.w;
            acc[6][0] += a1.z * b.x; acc[6][1] += a1.z * b.y; acc[6][2] += a1.z * b.z; acc[6][3] += a1.z * b.w;
            acc[7][0] += a1.w * b.x; acc[7][1] += a1.w * b.y; acc[7][2] += a1.w * b.z; acc[7][3] += a1.w * b.w;
        }
    }

#pragma unroll
    for (int i = 0; i < 8; ++i) {
        int node = mbase + tm * 8 + i;
        if (node < n) {
            float s = dinv[node] * qs;   // qs = QS2/QH1 folded by caller
            int q0 = __float2int_rn(fminf(fmaxf(acc[i][0] * s, -32767.f), 32767.f));
            int q1 = __float2int_rn(fminf(fmaxf(acc[i][1] * s, -32767.f), 32767.f));
            int q2 = __float2int_rn(fminf(fmaxf(acc[i][2] * s, -32767.f), 32767.f));
            int q3 = __float2int_rn(fminf(fmaxf(acc[i][3] * s, -32767.f), 32767.f));
            int2 pk;
            pk.x = (q0 & 0xffff) | (q1 << 16);
            pk.y = (q2 & 0xffff) | (q3 << 16);
            *reinterpret_cast<int2*>(outq + (size_t)node * HID + tc * 4) = pk;
        }
    }
}

// ---------------- gather core on int16 rows: exact integer aggregation ----------------
__device__ __forceinline__ float4 gather_node_q(
    const int2* __restrict__ hq, const int* __restrict__ row_ptr, const int* __restrict__ col,
    const float* __restrict__ dinv, float4 bv, float qinv, int node, int cl) {
    int beg = row_ptr[node];
    int end = row_ptr[node + 1];

    int2 sp = hq[(size_t)node * 16 + cl];      // self-loop
    int4 a0 = make_int4((sp.x << 16) >> 16, sp.x >> 16, (sp.y << 16) >> 16, sp.y >> 16);
    int4 a1 = make_int4(0, 0, 0, 0);
    int4 a2 = make_int4(0, 0, 0, 0);
    int4 a3 = make_int4(0, 0, 0, 0);

    int e = beg;
    for (; e + 8 <= end; e += 8) {
        int s0 = col[e], s1 = col[e + 1], s2 = col[e + 2], s3 = col[e + 3];
        int s4 = col[e + 4], s5 = col[e + 5], s6 = col[e + 6], s7 = col[e + 7];
        int2 v0 = hq[(size_t)s0 * 16 + cl];
        int2 v1 = hq[(size_t)s1 * 16 + cl];
        int2 v2 = hq[(size_t)s2 * 16 + cl];
        int2 v3 = hq[(size_t)s3 * 16 + cl];
        int2 v4 = hq[(size_t)s4 * 16 + cl];
        int2 v5 = hq[(size_t)s5 * 16 + cl];
        int2 v6 = hq[(size_t)s6 * 16 + cl];
        int2 v7 = hq[(size_t)s7 * 16 + cl];
        a0.x += (v0.x << 16) >> 16; a0.y += v0.x >> 16; a0.z += (v0.y << 16) >> 16; a0.w += v0.y >> 16;
        a1.x += (v1.x << 16) >> 16; a1.y += v1.x >> 16; a1.z += (v1.y << 16) >> 16; a1.w += v1.y >> 16;
        a2.x += (v2.x << 16) >> 16; a2.y += v2.x >> 16; a2.z += (v2.y << 16) >> 16; a2.w += v2.y >> 16;
        a3.x += (v3.x << 16) >> 16; a3.y += v3.x >> 16; a3.z += (v3.y << 16) >> 16; a3.w += v3.y >> 16;
        a0.x += (v4.x << 16) >> 16; a0.y += v4.x >> 16; a0.z += (v4.y << 16) >> 16; a0.w += v4.y >> 16;
        a1.x += (v5.x << 16) >> 16; a1.y += v5.x >> 16; a1.z += (v5.y << 16) >> 16; a1.w += v5.y >> 16;
        a2.x += (v6.x << 16) >> 16; a2.y += v6.x >> 16; a2.z += (v6.y << 16) >> 16; a2.w += v6.y >> 16;
        a3.x += (v7.x << 16) >> 16; a3.y += v7.x >> 16; a3.z += (v7.y << 16) >> 16; a3.w += v7.y >> 16;
    }
    for (; e + 4 <= end; e += 4) {
        int s0 = col[e], s1 = col[e + 1], s2 = col[e + 2], s3 = col[e + 3];
        int2 v0 = hq[(size_t)s0 * 16 + cl];
        int2 v1 = hq[(size_t)s1 * 16 + cl];
        int2 v2 = hq[(size_t)s2 * 16 + cl];
        int2 v3 = hq[(size_t)s3 * 16 + cl];
        a0.x += (v0.x << 16) >> 16; a0.y += v0.x >> 16; a0.z += (v0.y << 16) >> 16; a0.w += v0.y >> 16;
        a1.x += (v1.x << 16) >> 16; a1.y += v1.x >> 16; a1.z += (v1.y << 16) >> 16; a1.w += v1.y >> 16;
        a2.x += (v2.x << 16) >> 16; a2.y += v2.x >> 16; a2.z += (v2.y << 16) >> 16; a2.w += v2.y >> 16;
        a3.x += (v3.x << 16) >> 16; a3.y += v3.x >> 16; a3.z += (v3.y << 16) >> 16; a3.w += v3.y >> 16;
    }
    for (; e < end; ++e) {
        int2 v = hq[(size_t)col[e] * 16 + cl];
        a0.x += (v.x << 16) >> 16; a0.y += v.x >> 16; a0.z += (v.y << 16) >> 16; a0.w += v.y >> 16;
    }

    float sq = dinv[node] * qinv;
    float4 r;
    r.x = fmaf((float)((a0.x + a1.x) + (a2.x + a3.x)), sq, bv.x);
    r.y = fmaf((float)((a0.y + a1.y) + (a2.y + a3.y)), sq, bv.y);
    r.z = fmaf((float)((a0.z + a1.z) + (a2.z + a3.z)), sq, bv.z);
    r.w = fmaf((float)((a0.w + a1.w) + (a2.w + a3.w)), sq, bv.w);
    r.x = r.x > 0.f ? r.x : 0.f;
    r.y = r.y > 0.f ? r.y : 0.f;
    r.z = r.z > 0.f ? r.z : 0.f;
    r.w = r.w > 0.f ? r.w : 0.f;
    return r;
}

// full gather (layer 1): int16 in, int16 out; exactly one 4-node group per wave
__global__ void __launch_bounds__(256) gather_kernel(
    const short* __restrict__ hsq, const int* __restrict__ row_ptr, const int* __restrict__ col,
    const float* __restrict__ dinv, const float* __restrict__ b, float qinv, float qh,
    short* __restrict__ outq, int n) {
    const int2* __restrict__ hq = (const int2*)hsq;
    const int lane = threadIdx.x & 63;
    const int sub = lane >> 4;
    const int cl  = lane & 15;
    const int g = blockIdx.x * 4 + (threadIdx.x >> 6);

    int node = g * 4 + sub;
    if (node >= n) return;
    float4 bv = ((const float4*)b)[cl];
    float4 r = gather_node_q(hq, row_ptr, col, dinv, bv, qinv, node, cl);
    int q0 = __float2int_rn(fminf(r.x * qh, 32767.f));   // r >= 0 post-relu
    int q1 = __float2int_rn(fminf(r.y * qh, 32767.f));
    int q2 = __float2int_rn(fminf(r.z * qh, 32767.f));
    int q3 = __float2int_rn(fminf(r.w * qh, 32767.f));
    int2 pk;
    pk.x = (q0 & 0xffff) | (q1 << 16);
    pk.y = (q2 & 0xffff) | (q3 << 16);
    *((int2*)outq + (size_t)node * 16 + cl) = pk;
}

// fused sparse gather + prediction head: wave = 2 pairs; subs {u0,m0,u1,m1}
__global__ void __launch_bounds__(256) gather_final_kernel(
    const short* __restrict__ hsq, const int* __restrict__ row_ptr, const int* __restrict__ col,
    const int* __restrict__ users, const int* __restrict__ movies,
    const float* __restrict__ dinv, const float* __restrict__ b, float qinv,
    const float* __restrict__ fc_w, const float* __restrict__ fc_b,
    float* __restrict__ out, int batch) {
    const int2* __restrict__ hq = (const int2*)hsq;
    const int lane = threadIdx.x & 63;
    const int sub = lane >> 4;
    const int cl  = lane & 15;
    const int g = blockIdx.x * 4 + (threadIdx.x >> 6);

    int pair = g * 2 + (sub >> 1);
    int node = 0;   // dummy (valid memory) so all lanes participate in shuffles
    if (pair < batch) node = ((sub & 1) == 0) ? users[pair] : movies[pair];

    float4 bv = ((const float4*)b)[cl];
    float4 r = gather_node_q(hq, row_ptr, col, dinv, bv, qinv, node, cl);

    // three-way elementwise product with the partner sub (u<->m) and fc_w
    float4 fw = ((const float4*)fc_w)[cl];
    float px = __shfl_xor(r.x, 16, 64);
    float py = __shfl_xor(r.y, 16, 64);
    float pz = __shfl_xor(r.z, 16, 64);
    float pw = __shfl_xor(r.w, 16, 64);
    float s = r.x * px * fw.x + r.y * py * fw.y + r.z * pz * fw.z + r.w * pw * fw.w;
#pragma unroll
    for (int off = 1; off < 16; off <<= 1)
        s += __shfl_xor(s, off, 64);

    if ((lane & 31) == 0) {
        int pr = g * 2 + (lane >> 5);
        if (pr < batch) out[pr] = s + fc_b[0];
    }
}

extern "C" void kernel_launch(void* const* d_in, const int* in_sizes, int n_in,
                              void* d_out, int out_size, void* d_ws, size_t ws_size,
                              hipStream_t stream) {
    const float* x     = (const float*)d_in[0];
    const int*   edge  = (const int*)d_in[1];   // [2][E]
    const int*   users = (const int*)d_in[2];
    const int*   movies= (const int*)d_in[3];
    const float* W1    = (const float*)d_in[4];
    const float* b1    = (const float*)d_in[5];
    const float* W2    = (const float*)d_in[6];
    const float* b2    = (const float*)d_in[7];
    const float* fc_w  = (const float*)d_in[8];
    const float* fc_b  = (const float*)d_in[9];
    float* out = (float*)d_out;

    const int IN_DIM = 128;
    const int n       = in_sizes[0] / IN_DIM;  // 100000
    const int n_edges = in_sizes[1] / 2;       // 1200000 (divisible by 4)
    const int batch   = in_sizes[2];           // 8192

    const int* esrc = edge;
    const int* edst = edge + n_edges;

    int n4   = n_edges / 4;                    // 300000
    int EPB4 = (n4 + NBLKC - 1) / NBLKC;       // 586 int4 per block
    int NB   = (n + 255) >> 8;                 // 391 buckets
    const int HLEN = NB * NBLKC;               // 200192

    char* ws = (char*)d_ws;
    size_t o = 0;
    auto alloc = [&](size_t bytes) { void* p = ws + o; o = (o + bytes + 255) & ~(size_t)255; return p; };
    int*   hist    = (int*)  alloc(sizeof(int) * HLEN);
    int*   tmp     = (int*)  alloc(sizeof(int) * HLEN);
    int*   bsum    = (int*)  alloc(sizeof(int) * NBLKC);
    int*   boff    = (int*)  alloc(sizeof(int) * NBLKC);
    int*   sorted  = (int*)  alloc(sizeof(int) * n_edges);   // packed (src<<8)|(dst&255)
    int*   col     = (int*)  alloc(sizeof(int) * n_edges);
    int*   row_ptr = (int*)  alloc(sizeof(int) * (n + 1));
    float* dinv    = (float*)alloc(sizeof(float) * n);
    short* Bq      = (short*)alloc(sizeof(short) * (size_t)n * HID);  // q(hs1) then q(hs2)
    short* Hq      = (short*)alloc(sizeof(short) * (size_t)n * HID);  // q(h1)

    // ---- fused cooperative CSR build + norm ----
    {
        const int4* src4 = (const int4*)esrc;
        const int4* dst4 = (const int4*)edst;
        int ne = n_edges, nn = n;
        void* args[] = { (void*)&src4, (void*)&dst4, (void*)&hist, (void*)&tmp,
                         (void*)&bsum, (void*)&boff, (void*)&sorted, (void*)&row_ptr,
                         (void*)&dinv, (void*)&col, (void*)&n4, (void*)&nn,
                         (void*)&ne, (void*)&EPB4, (void*)&NB };
        hipLaunchCooperativeKernel((void*)build_fused_kernel, dim3(NBLKC), dim3(256),
                                   args, 0, stream);
    }

    const int ngroups = (n + 3) >> 2;              // 25000
    const int gather_blocks = (ngroups + 3) / 4;   // 6250 (one group per wave)
    const int head_blocks = (batch + 7) / 8;       // 1024 (2 pairs per wave)

    // ---- layer 1 ----
    gemm_tile_kernel<128><<<(n + 127) / 128, 256, 0, stream>>>(x, W1, dinv, Bq, QS1, n);     // Bq = q(hs1)
    gather_kernel<<<gather_blocks, 256, 0, stream>>>(Bq, row_ptr, col, dinv, b1,
                                                     QINV1, QH1, Hq, n);                     // Hq = q(h1)

    // ---- layer 2 ----
    gemm_tile_q_kernel<<<(n + 127) / 128, 256, 0, stream>>>(Hq, W2, dinv, Bq, QS2 / QH1, n); // Bq = q(hs2)
    gather_final_kernel<<<head_blocks, 256, 0, stream>>>(Bq, row_ptr, col, users, movies,
                                                         dinv, b2, QINV2, fc_w, fc_b,
                                                         out, batch);                        // out = scores
}

// Round 17
// 142.684 us; speedup vs baseline: 2.6676x; 2.6676x over previous
//
#include <hip/hip_runtime.h>

#define HID 64

// int16 quantization scales
#define QS1   4096.0f   // hs1 range +-8
#define QINV1 (1.0f/4096.0f)
#define QH1   2048.0f   // h1 range +-16
#define QS2   2048.0f   // hs2 range +-16
#define QINV2 (1.0f/2048.0f)

// ================= atomic-free CSR build via bucket counting-sort (5 dispatches) ==========
// Buckets of 256 consecutive dst nodes; NB = ceil(n/256). NBLK=512 edge blocks.
// hist/tmp layout: [bucket][block], bucket-major. scanned = tmp + boff (inline, >>11).
// sorted entries packed: (src << 8) | (dst & 255)   (src < 2^17 fits in 25 bits)

__global__ void __launch_bounds__(256) hist_kernel(
    const int4* __restrict__ dst4, int* __restrict__ hist, int n4, int nblk, int nb, int epb4) {
    __shared__ int h[512];
    const int tid = threadIdx.x, blk = blockIdx.x;
    h[tid] = 0; h[tid + 256] = 0;
    __syncthreads();
    const int beg4 = blk * epb4;
    const int end4 = min(n4, beg4 + epb4);
    for (int j = beg4 + tid; j < end4; j += 256) {
        int4 d = dst4[j];
        atomicAdd(&h[d.x >> 8], 1);
        atomicAdd(&h[d.y >> 8], 1);
        atomicAdd(&h[d.z >> 8], 1);
        atomicAdd(&h[d.w >> 8], 1);
    }
    __syncthreads();
    for (int b = tid; b < nb; b += 256) hist[b * nblk + blk] = h[b];
}

// two-level scan, 2 elements per thread (2048 per block) so <=128 scan blocks at HLEN~200K
__global__ void __launch_bounds__(1024) scan_partial_kernel(
    const int* __restrict__ in, int* __restrict__ tmp, int* __restrict__ bsum, int n) {
    __shared__ int sm[1024];
    const int tid = threadIdx.x;
    int i0 = blockIdx.x * 2048 + tid * 2;
    int a = (i0 < n) ? in[i0] : 0;
    int b = (i0 + 1 < n) ? in[i0 + 1] : 0;
    int v = a + b;
    sm[tid] = v;
    __syncthreads();
#pragma unroll
    for (int off = 1; off < 1024; off <<= 1) {
        int t = (tid >= off) ? sm[tid - off] : 0;
        __syncthreads();
        sm[tid] += t;
        __syncthreads();
    }
    int excl = sm[tid] - v;
    if (i0 < n) tmp[i0] = excl;
    if (i0 + 1 < n) tmp[i0 + 1] = excl + a;
    if (tid == 1023) bsum[blockIdx.x] = sm[1023];
}

__global__ void __launch_bounds__(128) scan_sums_kernel(
    const int* __restrict__ bsum, int* __restrict__ boff, int nb) {
    __shared__ int sm[128];
    const int tid = threadIdx.x;
    int v = (tid < nb) ? bsum[tid] : 0;
    sm[tid] = v;
    __syncthreads();
#pragma unroll
    for (int off = 1; off < 128; off <<= 1) {
        int t = (tid >= off) ? sm[tid - off] : 0;
        __syncthreads();
        sm[tid] += t;
        __syncthreads();
    }
    boff[tid] = sm[tid] - v;
}

__device__ __forceinline__ int scanned_at(const int* tmp, const int* boff, int idx) {
    return tmp[idx] + boff[idx >> 11];   // scan blocks cover 2048 elements
}

__global__ void __launch_bounds__(256) partition_kernel(
    const int4* __restrict__ src4, const int4* __restrict__ dst4,
    const int* __restrict__ tmp, const int* __restrict__ boff,
    int* __restrict__ sorted, int n4, int nblk, int nb, int epb4) {
    __shared__ int cur[512];
    const int tid = threadIdx.x, blk = blockIdx.x;
    for (int b = tid; b < nb; b += 256) cur[b] = scanned_at(tmp, boff, b * nblk + blk);
    __syncthreads();
    const int beg4 = blk * epb4;
    const int end4 = min(n4, beg4 + epb4);
    for (int j = beg4 + tid; j < end4; j += 256) {
        int4 d = dst4[j];
        int4 s = src4[j];
        int p0 = atomicAdd(&cur[d.x >> 8], 1);
        int p1 = atomicAdd(&cur[d.y >> 8], 1);
        int p2 = atomicAdd(&cur[d.z >> 8], 1);
        int p3 = atomicAdd(&cur[d.w >> 8], 1);
        sorted[p0] = (s.x << 8) | (d.x & 255);
        sorted[p1] = (s.y << 8) | (d.y & 255);
        sorted[p2] = (s.z << 8) | (d.z & 255);
        sorted[p3] = (s.w << 8) | (d.w & 255);
    }
}

#define BKCAP 4096
__global__ void __launch_bounds__(256) bucket_build_kernel(
    const int* __restrict__ sorted, const int* __restrict__ tmp, const int* __restrict__ boff,
    int* __restrict__ row_ptr, float* __restrict__ dinv, int* __restrict__ col,
    int nblk, int n, int n_edges) {
    __shared__ int cnt[256], sc[256], cur[256];
    __shared__ int ecache[BKCAP];
    const int b = blockIdx.x, tid = threadIdx.x;
    const int base = scanned_at(tmp, boff, b * nblk);
    const int end  = (b == gridDim.x - 1) ? n_edges : scanned_at(tmp, boff, (b + 1) * nblk);
    const int m = end - base;
    const bool fits = (m <= BKCAP);

    cnt[tid] = 0;
    __syncthreads();
    if (fits) {
        for (int e = tid; e < m; e += 256) {
            int v = sorted[base + e];
            ecache[e] = v;
            atomicAdd(&cnt[v & 255], 1);
        }
    } else {
        for (int e = base + tid; e < end; e += 256)
            atomicAdd(&cnt[sorted[e] & 255], 1);
    }
    __syncthreads();

    sc[tid] = cnt[tid];
    __syncthreads();
#pragma unroll
    for (int off = 1; off < 256; off <<= 1) {
        int t = (tid >= off) ? sc[tid - off] : 0;
        __syncthreads();
        sc[tid] += t;
        __syncthreads();
    }
    int ex = sc[tid] - cnt[tid];
    cur[tid] = ex;

    int node = b * 256 + tid;
    if (node < n) {
        row_ptr[node] = base + ex;
        dinv[node] = rsqrtf((float)(cnt[tid] + 1));   // +1 = self-loop
    }
    if (b == gridDim.x - 1 && tid == 0) row_ptr[n] = n_edges;
    __syncthreads();

    if (fits) {
        for (int e = tid; e < m; e += 256) {
            int v = ecache[e];
            int lp = atomicAdd(&cur[v & 255], 1);
            col[base + lp] = v >> 8;
        }
    } else {
        for (int e = base + tid; e < end; e += 256) {
            int v = sorted[e];
            int lp = atomicAdd(&cur[v & 255], 1);
            col[base + lp] = v >> 8;
        }
    }
}

// ---------------- gemm1 (fp32 in, int16 out): hsq = q(dinv * X@W^T) ----------------
template<int K>
__global__ void __launch_bounds__(256) gemm_tile_kernel(
    const float* __restrict__ X, const float* __restrict__ W,
    const float* __restrict__ dinv, short* __restrict__ outq, float qs, int n) {
    constexpr int BK = 32;
    constexpr int NKB = K / BK;
    __shared__ float As[BK][132];
    __shared__ float Bs[BK][68];

    const int t = threadIdx.x;
    const int mbase = blockIdx.x * 128;
    const int tc = t & 15;
    const int tm = t >> 4;
    const int lr = t >> 3;
    const int k4 = (t & 7) * 4;

    float acc[8][4] = {};

    for (int kb = 0; kb < NKB; ++kb) {
        __syncthreads();
#pragma unroll
        for (int h = 0; h < 4; ++h) {
            int m = lr + h * 32;
            int node = mbase + m;
            float4 v = make_float4(0.f, 0.f, 0.f, 0.f);
            if (node < n)
                v = *reinterpret_cast<const float4*>(X + (size_t)node * K + kb * BK + k4);
            As[k4 + 0][m] = v.x; As[k4 + 1][m] = v.y;
            As[k4 + 2][m] = v.z; As[k4 + 3][m] = v.w;
        }
#pragma unroll
        for (int h = 0; h < 2; ++h) {
            int c = lr + h * 32;
            float4 wv = *reinterpret_cast<const float4*>(W + (size_t)c * K + kb * BK + k4);
            Bs[k4 + 0][c] = wv.x; Bs[k4 + 1][c] = wv.y;
            Bs[k4 + 2][c] = wv.z; Bs[k4 + 3][c] = wv.w;
        }
        __syncthreads();
#pragma unroll
        for (int k = 0; k < BK; ++k) {
            float4 a0 = *reinterpret_cast<const float4*>(&As[k][tm * 8]);
            float4 a1 = *reinterpret_cast<const float4*>(&As[k][tm * 8 + 4]);
            float4 b = *reinterpret_cast<const float4*>(&Bs[k][tc * 4]);
            acc[0][0] += a0.x * b.x; acc[0][1] += a0.x * b.y; acc[0][2] += a0.x * b.z; acc[0][3] += a0.x * b.w;
            acc[1][0] += a0.y * b.x; acc[1][1] += a0.y * b.y; acc[1][2] += a0.y * b.z; acc[1][3] += a0.y * b.w;
            acc[2][0] += a0.z * b.x; acc[2][1] += a0.z * b.y; acc[2][2] += a0.z * b.z; acc[2][3] += a0.z * b.w;
            acc[3][0] += a0.w * b.x; acc[3][1] += a0.w * b.y; acc[3][2] += a0.w * b.z; acc[3][3] += a0.w * b.w;
            acc[4][0] += a1.x * b.x; acc[4][1] += a1.x * b.y; acc[4][2] += a1.x * b.z; acc[4][3] += a1.x * b.w;
            acc[5][0] += a1.y * b.x; acc[5][1] += a1.y * b.y; acc[5][2] += a1.y * b.z; acc[5][3] += a1.y * b.w;
            acc[6][0] += a1.z * b.x; acc[6][1] += a1.z * b.y; acc[6][2] += a1.z * b.z; acc[6][3] += a1.z * b.w;
            acc[7][0] += a1.w * b.x; acc[7][1] += a1.w * b.y; acc[7][2] += a1.w * b.z; acc[7][3] += a1.w * b.w;
        }
    }

#pragma unroll
    for (int i = 0; i < 8; ++i) {
        int node = mbase + tm * 8 + i;
        if (node < n) {
            float s = dinv[node] * qs;
            int q0 = __float2int_rn(fminf(fmaxf(acc[i][0] * s, -32767.f), 32767.f));
            int q1 = __float2int_rn(fminf(fmaxf(acc[i][1] * s, -32767.f), 32767.f));
            int q2 = __float2int_rn(fminf(fmaxf(acc[i][2] * s, -32767.f), 32767.f));
            int q3 = __float2int_rn(fminf(fmaxf(acc[i][3] * s, -32767.f), 32767.f));
            int2 pk;
            pk.x = (q0 & 0xffff) | (q1 << 16);
            pk.y = (q2 & 0xffff) | (q3 << 16);
            *reinterpret_cast<int2*>(outq + (size_t)node * HID + tc * 4) = pk;
        }
    }
}

// ---------------- gemm2 (int16 in, int16 out), K=64: hs2q = q(dinv * h1 @ W2^T) ----------------
__global__ void __launch_bounds__(256) gemm_tile_q_kernel(
    const short* __restrict__ Xq, const float* __restrict__ W,
    const float* __restrict__ dinv, short* __restrict__ outq, float qs, int n) {
    constexpr int K = 64, BK = 32, NKB = 2;
    __shared__ float As[BK][132];
    __shared__ float Bs[BK][68];

    const int t = threadIdx.x;
    const int mbase = blockIdx.x * 128;
    const int tc = t & 15;
    const int tm = t >> 4;
    const int lr = t >> 3;
    const int k4 = (t & 7) * 4;

    float acc[8][4] = {};

    for (int kb = 0; kb < NKB; ++kb) {
        __syncthreads();
#pragma unroll
        for (int h = 0; h < 4; ++h) {
            int m = lr + h * 32;
            int node = mbase + m;
            int2 raw = make_int2(0, 0);
            if (node < n)
                raw = *reinterpret_cast<const int2*>(Xq + (size_t)node * K + kb * BK + k4);
            As[k4 + 0][m] = (float)((raw.x << 16) >> 16);
            As[k4 + 1][m] = (float)(raw.x >> 16);
            As[k4 + 2][m] = (float)((raw.y << 16) >> 16);
            As[k4 + 3][m] = (float)(raw.y >> 16);
        }
#pragma unroll
        for (int h = 0; h < 2; ++h) {
            int c = lr + h * 32;
            float4 wv = *reinterpret_cast<const float4*>(W + (size_t)c * K + kb * BK + k4);
            Bs[k4 + 0][c] = wv.x; Bs[k4 + 1][c] = wv.y;
            Bs[k4 + 2][c] = wv.z; Bs[k4 + 3][c] = wv.w;
        }
        __syncthreads();
#pragma unroll
        for (int k = 0; k < BK; ++k) {
            float4 a0 = *reinterpret_cast<const float4*>(&As[k][tm * 8]);
            float4 a1 = *reinterpret_cast<const float4*>(&As[k][tm * 8 + 4]);
            float4 b = *reinterpret_cast<const float4*>(&Bs[k][tc * 4]);
            acc[0][0] += a0.x * b.x; acc[0][1] += a0.x * b.y; acc[0][2] += a0.x * b.z; acc[0][3] += a0.x * b.w;
            acc[1][0] += a0.y * b.x; acc[1][1] += a0.y * b.y; acc[1][2] += a0.y * b.z; acc[1][3] += a0.y * b.w;
            acc[2][0] += a0.z * b.x; acc[2][1] += a0.z * b.y; acc[2][2] += a0.z * b.z; acc[2][3] += a0.z * b.w;
            acc[3][0] += a0.w * b.x; acc[3][1] += a0.w * b.y; acc[3][2] += a0.w * b.z; acc[3][3] += a0.w * b.w;
            acc[4][0] += a1.x * b.x; acc[4][1] += a1.x * b.y; acc[4][2] += a1.x * b.z; acc[4][3] += a1.x * b.w;
            acc[5][0] += a1.y * b.x; acc[5][1] += a1.y * b.y; acc[5][2] += a1.y * b.z; acc[5][3] += a1.y * b.w;
            acc[6][0] += a1.z * b.x; acc[6][1] += a1.z * b.y; acc[6][2] += a1.z * b.z; acc[6][3] += a1.z * b.w;
            acc[7][0] += a1.w * b.x; acc[7][1] += a1.w * b.y; acc[7][2] += a1.w * b.z; acc[7][3] += a1.w * b.w;
        }
    }

#pragma unroll
    for (int i = 0; i < 8; ++i) {
        int node = mbase + tm * 8 + i;
        if (node < n) {
            float s = dinv[node] * qs;   // qs = QS2/QH1 folded by caller
            int q0 = __float2int_rn(fminf(fmaxf(acc[i][0] * s, -32767.f), 32767.f));
            int q1 = __float2int_rn(fminf(fmaxf(acc[i][1] * s, -32767.f), 32767.f));
            int q2 = __float2int_rn(fminf(fmaxf(acc[i][2] * s, -32767.f), 32767.f));
            int q3 = __float2int_rn(fminf(fmaxf(acc[i][3] * s, -32767.f), 32767.f));
            int2 pk;
            pk.x = (q0 & 0xffff) | (q1 << 16);
            pk.y = (q2 & 0xffff) | (q3 << 16);
            *reinterpret_cast<int2*>(outq + (size_t)node * HID + tc * 4) = pk;
        }
    }
}

// ---------------- gather core on int16 rows: exact integer aggregation ----------------
__device__ __forceinline__ float4 gather_node_q(
    const int2* __restrict__ hq, const int* __restrict__ row_ptr, const int* __restrict__ col,
    const float* __restrict__ dinv, float4 bv, float qinv, int node, int cl) {
    int beg = row_ptr[node];
    int end = row_ptr[node + 1];

    int2 sp = hq[(size_t)node * 16 + cl];      // self-loop
    int4 a0 = make_int4((sp.x << 16) >> 16, sp.x >> 16, (sp.y << 16) >> 16, sp.y >> 16);
    int4 a1 = make_int4(0, 0, 0, 0);
    int4 a2 = make_int4(0, 0, 0, 0);
    int4 a3 = make_int4(0, 0, 0, 0);

    int e = beg;
    for (; e + 8 <= end; e += 8) {
        int s0 = col[e], s1 = col[e + 1], s2 = col[e + 2], s3 = col[e + 3];
        int s4 = col[e + 4], s5 = col[e + 5], s6 = col[e + 6], s7 = col[e + 7];
        int2 v0 = hq[(size_t)s0 * 16 + cl];
        int2 v1 = hq[(size_t)s1 * 16 + cl];
        int2 v2 = hq[(size_t)s2 * 16 + cl];
        int2 v3 = hq[(size_t)s3 * 16 + cl];
        int2 v4 = hq[(size_t)s4 * 16 + cl];
        int2 v5 = hq[(size_t)s5 * 16 + cl];
        int2 v6 = hq[(size_t)s6 * 16 + cl];
        int2 v7 = hq[(size_t)s7 * 16 + cl];
        a0.x += (v0.x << 16) >> 16; a0.y += v0.x >> 16; a0.z += (v0.y << 16) >> 16; a0.w += v0.y >> 16;
        a1.x += (v1.x << 16) >> 16; a1.y += v1.x >> 16; a1.z += (v1.y << 16) >> 16; a1.w += v1.y >> 16;
        a2.x += (v2.x << 16) >> 16; a2.y += v2.x >> 16; a2.z += (v2.y << 16) >> 16; a2.w += v2.y >> 16;
        a3.x += (v3.x << 16) >> 16; a3.y += v3.x >> 16; a3.z += (v3.y << 16) >> 16; a3.w += v3.y >> 16;
        a0.x += (v4.x << 16) >> 16; a0.y += v4.x >> 16; a0.z += (v4.y << 16) >> 16; a0.w += v4.y >> 16;
        a1.x += (v5.x << 16) >> 16; a1.y += v5.x >> 16; a1.z += (v5.y << 16) >> 16; a1.w += v5.y >> 16;
        a2.x += (v6.x << 16) >> 16; a2.y += v6.x >> 16; a2.z += (v6.y << 16) >> 16; a2.w += v6.y >> 16;
        a3.x += (v7.x << 16) >> 16; a3.y += v7.x >> 16; a3.z += (v7.y << 16) >> 16; a3.w += v7.y >> 16;
    }
    for (; e + 4 <= end; e += 4) {
        int s0 = col[e], s1 = col[e + 1], s2 = col[e + 2], s3 = col[e + 3];
        int2 v0 = hq[(size_t)s0 * 16 + cl];
        int2 v1 = hq[(size_t)s1 * 16 + cl];
        int2 v2 = hq[(size_t)s2 * 16 + cl];
        int2 v3 = hq[(size_t)s3 * 16 + cl];
        a0.x += (v0.x << 16) >> 16; a0.y += v0.x >> 16; a0.z += (v0.y << 16) >> 16; a0.w += v0.y >> 16;
        a1.x += (v1.x << 16) >> 16; a1.y += v1.x >> 16; a1.z += (v1.y << 16) >> 16; a1.w += v1.y >> 16;
        a2.x += (v2.x << 16) >> 16; a2.y += v2.x >> 16; a2.z += (v2.y << 16) >> 16; a2.w += v2.y >> 16;
        a3.x += (v3.x << 16) >> 16; a3.y += v3.x >> 16; a3.z += (v3.y << 16) >> 16; a3.w += v3.y >> 16;
    }
    for (; e < end; ++e) {
        int2 v = hq[(size_t)col[e] * 16 + cl];
        a0.x += (v.x << 16) >> 16; a0.y += v.x >> 16; a0.z += (v.y << 16) >> 16; a0.w += v.y >> 16;
    }

    float sq = dinv[node] * qinv;
    float4 r;
    r.x = fmaf((float)((a0.x + a1.x) + (a2.x + a3.x)), sq, bv.x);
    r.y = fmaf((float)((a0.y + a1.y) + (a2.y + a3.y)), sq, bv.y);
    r.z = fmaf((float)((a0.z + a1.z) + (a2.z + a3.z)), sq, bv.z);
    r.w = fmaf((float)((a0.w + a1.w) + (a2.w + a3.w)), sq, bv.w);
    r.x = r.x > 0.f ? r.x : 0.f;
    r.y = r.y > 0.f ? r.y : 0.f;
    r.z = r.z > 0.f ? r.z : 0.f;
    r.w = r.w > 0.f ? r.w : 0.f;
    return r;
}

// full gather (layer 1): int16 in, int16 out; exactly one 4-node group per wave
__global__ void __launch_bounds__(256) gather_kernel(
    const short* __restrict__ hsq, const int* __restrict__ row_ptr, const int* __restrict__ col,
    const float* __restrict__ dinv, const float* __restrict__ b, float qinv, float qh,
    short* __restrict__ outq, int n) {
    const int2* __restrict__ hq = (const int2*)hsq;
    const int lane = threadIdx.x & 63;
    const int sub = lane >> 4;
    const int cl  = lane & 15;
    const int g = blockIdx.x * 4 + (threadIdx.x >> 6);

    int node = g * 4 + sub;
    if (node >= n) return;
    float4 bv = ((const float4*)b)[cl];
    float4 r = gather_node_q(hq, row_ptr, col, dinv, bv, qinv, node, cl);
    int q0 = __float2int_rn(fminf(r.x * qh, 32767.f));   // r >= 0 post-relu
    int q1 = __float2int_rn(fminf(r.y * qh, 32767.f));
    int q2 = __float2int_rn(fminf(r.z * qh, 32767.f));
    int q3 = __float2int_rn(fminf(r.w * qh, 32767.f));
    int2 pk;
    pk.x = (q0 & 0xffff) | (q1 << 16);
    pk.y = (q2 & 0xffff) | (q3 << 16);
    *((int2*)outq + (size_t)node * 16 + cl) = pk;
}

// fused sparse gather + prediction head: wave = 2 pairs; subs {u0,m0,u1,m1}
__global__ void __launch_bounds__(256) gather_final_kernel(
    const short* __restrict__ hsq, const int* __restrict__ row_ptr, const int* __restrict__ col,
    const int* __restrict__ users, const int* __restrict__ movies,
    const float* __restrict__ dinv, const float* __restrict__ b, float qinv,
    const float* __restrict__ fc_w, const float* __restrict__ fc_b,
    float* __restrict__ out, int batch) {
    const int2* __restrict__ hq = (const int2*)hsq;
    const int lane = threadIdx.x & 63;
    const int sub = lane >> 4;
    const int cl  = lane & 15;
    const int g = blockIdx.x * 4 + (threadIdx.x >> 6);

    int pair = g * 2 + (sub >> 1);
    int node = 0;   // dummy (valid memory) so all lanes participate in shuffles
    if (pair < batch) node = ((sub & 1) == 0) ? users[pair] : movies[pair];

    float4 bv = ((const float4*)b)[cl];
    float4 r = gather_node_q(hq, row_ptr, col, dinv, bv, qinv, node, cl);

    // three-way elementwise product with the partner sub (u<->m) and fc_w
    float4 fw = ((const float4*)fc_w)[cl];
    float px = __shfl_xor(r.x, 16, 64);
    float py = __shfl_xor(r.y, 16, 64);
    float pz = __shfl_xor(r.z, 16, 64);
    float pw = __shfl_xor(r.w, 16, 64);
    float s = r.x * px * fw.x + r.y * py * fw.y + r.z * pz * fw.z + r.w * pw * fw.w;
#pragma unroll
    for (int off = 1; off < 16; off <<= 1)
        s += __shfl_xor(s, off, 64);

    if ((lane & 31) == 0) {
        int pr = g * 2 + (lane >> 5);
        if (pr < batch) out[pr] = s + fc_b[0];
    }
}

extern "C" void kernel_launch(void* const* d_in, const int* in_sizes, int n_in,
                              void* d_out, int out_size, void* d_ws, size_t ws_size,
                              hipStream_t stream) {
    const float* x     = (const float*)d_in[0];
    const int*   edge  = (const int*)d_in[1];   // [2][E]
    const int*   users = (const int*)d_in[2];
    const int*   movies= (const int*)d_in[3];
    const float* W1    = (const float*)d_in[4];
    const float* b1    = (const float*)d_in[5];
    const float* W2    = (const float*)d_in[6];
    const float* b2    = (const float*)d_in[7];
    const float* fc_w  = (const float*)d_in[8];
    const float* fc_b  = (const float*)d_in[9];
    float* out = (float*)d_out;

    const int IN_DIM = 128;
    const int n       = in_sizes[0] / IN_DIM;  // 100000
    const int n_edges = in_sizes[1] / 2;       // 1200000 (divisible by 4)
    const int batch   = in_sizes[2];           // 8192

    const int* esrc = edge;
    const int* edst = edge + n_edges;

    const int n4   = n_edges / 4;              // 300000
    const int NBLK = 512;                      // edge blocks for hist/partition
    const int EPB4 = (n4 + NBLK - 1) / NBLK;   // 586 int4 per block
    const int NB   = (n + 255) >> 8;           // 391 buckets
    const int HLEN = NB * NBLK;                // 200192
    const int SB   = (HLEN + 2047) / 2048;     // 98 scan blocks (<=128)

    char* ws = (char*)d_ws;
    size_t o = 0;
    auto alloc = [&](size_t bytes) { void* p = ws + o; o = (o + bytes + 255) & ~(size_t)255; return p; };
    int*   hist    = (int*)  alloc(sizeof(int) * HLEN);
    int*   tmp     = (int*)  alloc(sizeof(int) * HLEN);
    int*   bsum    = (int*)  alloc(sizeof(int) * 128);
    int*   boff    = (int*)  alloc(sizeof(int) * 128);
    int*   sorted  = (int*)  alloc(sizeof(int) * n_edges);   // packed (src<<8)|(dst&255)
    int*   col     = (int*)  alloc(sizeof(int) * n_edges);
    int*   row_ptr = (int*)  alloc(sizeof(int) * (n + 1));
    float* dinv    = (float*)alloc(sizeof(float) * n);
    short* Bq      = (short*)alloc(sizeof(short) * (size_t)n * HID);  // q(hs1) then q(hs2)
    short* Hq      = (short*)alloc(sizeof(short) * (size_t)n * HID);  // q(h1)

    // ---- atomic-free CSR build + norm (5 dispatches) ----
    hist_kernel<<<NBLK, 256, 0, stream>>>((const int4*)edst, hist, n4, NBLK, NB, EPB4);
    scan_partial_kernel<<<SB, 1024, 0, stream>>>(hist, tmp, bsum, HLEN);
    scan_sums_kernel<<<1, 128, 0, stream>>>(bsum, boff, SB);
    partition_kernel<<<NBLK, 256, 0, stream>>>((const int4*)esrc, (const int4*)edst,
                                               tmp, boff, sorted, n4, NBLK, NB, EPB4);
    bucket_build_kernel<<<NB, 256, 0, stream>>>(sorted, tmp, boff, row_ptr, dinv, col,
                                                NBLK, n, n_edges);

    const int ngroups = (n + 3) >> 2;              // 25000
    const int gather_blocks = (ngroups + 3) / 4;   // 6250 (one group per wave)
    const int head_blocks = (batch + 7) / 8;       // 1024 (2 pairs per wave)

    // ---- layer 1 ----
    gemm_tile_kernel<128><<<(n + 127) / 128, 256, 0, stream>>>(x, W1, dinv, Bq, QS1, n);     // Bq = q(hs1)
    gather_kernel<<<gather_blocks, 256, 0, stream>>>(Bq, row_ptr, col, dinv, b1,
                                                     QINV1, QH1, Hq, n);                     // Hq = q(h1)

    // ---- layer 2 ----
    gemm_tile_q_kernel<<<(n + 127) / 128, 256, 0, stream>>>(Hq, W2, dinv, Bq, QS2 / QH1, n); // Bq = q(hs2)
    gather_final_kernel<<<head_blocks, 256, 0, stream>>>(Bq, row_ptr, col, users, movies,
                                                         dinv, b2, QINV2, fc_w, fc_b,
                                                         out, batch);                        // out = scores
}

// Round 18
// 132.816 us; speedup vs baseline: 2.8658x; 1.0743x over previous
//
#include <hip/hip_runtime.h>

#define HID 64

// int16 quantization scales
#define QS1   4096.0f   // hs1 range +-8
#define QINV1 (1.0f/4096.0f)
#define QH1   2048.0f   // h1 range +-16
#define QS2   2048.0f   // hs2 range +-16
#define QINV2 (1.0f/2048.0f)

// ================= atomic-free CSR build via bucket counting-sort (5 dispatches) ==========
// Buckets of 256 consecutive dst nodes; NB = ceil(n/256). NBLK=512 edge blocks.
// hist/tmp layout: [bucket][block], bucket-major. scanned = tmp + boff (inline, >>11).
// sorted entries packed: (src << 8) | (dst & 255)   (src < 2^17 fits in 25 bits)

__global__ void __launch_bounds__(256) hist_kernel(
    const int4* __restrict__ dst4, int* __restrict__ hist, int n4, int nblk, int nb, int epb4) {
    __shared__ int h[512];
    const int tid = threadIdx.x, blk = blockIdx.x;
    h[tid] = 0; h[tid + 256] = 0;
    __syncthreads();
    const int beg4 = blk * epb4;
    const int end4 = min(n4, beg4 + epb4);
    for (int j = beg4 + tid; j < end4; j += 256) {
        int4 d = dst4[j];
        atomicAdd(&h[d.x >> 8], 1);
        atomicAdd(&h[d.y >> 8], 1);
        atomicAdd(&h[d.z >> 8], 1);
        atomicAdd(&h[d.w >> 8], 1);
    }
    __syncthreads();
    for (int b = tid; b < nb; b += 256) hist[b * nblk + blk] = h[b];
}

__global__ void __launch_bounds__(1024) scan_partial_kernel(
    const int* __restrict__ in, int* __restrict__ tmp, int* __restrict__ bsum, int n) {
    __shared__ int sm[1024];
    const int tid = threadIdx.x;
    int i0 = blockIdx.x * 2048 + tid * 2;
    int a = (i0 < n) ? in[i0] : 0;
    int b = (i0 + 1 < n) ? in[i0 + 1] : 0;
    int v = a + b;
    sm[tid] = v;
    __syncthreads();
#pragma unroll
    for (int off = 1; off < 1024; off <<= 1) {
        int t = (tid >= off) ? sm[tid - off] : 0;
        __syncthreads();
        sm[tid] += t;
        __syncthreads();
    }
    int excl = sm[tid] - v;
    if (i0 < n) tmp[i0] = excl;
    if (i0 + 1 < n) tmp[i0 + 1] = excl + a;
    if (tid == 1023) bsum[blockIdx.x] = sm[1023];
}

__global__ void __launch_bounds__(128) scan_sums_kernel(
    const int* __restrict__ bsum, int* __restrict__ boff, int nb) {
    __shared__ int sm[128];
    const int tid = threadIdx.x;
    int v = (tid < nb) ? bsum[tid] : 0;
    sm[tid] = v;
    __syncthreads();
#pragma unroll
    for (int off = 1; off < 128; off <<= 1) {
        int t = (tid >= off) ? sm[tid - off] : 0;
        __syncthreads();
        sm[tid] += t;
        __syncthreads();
    }
    boff[tid] = sm[tid] - v;
}

__device__ __forceinline__ int scanned_at(const int* tmp, const int* boff, int idx) {
    return tmp[idx] + boff[idx >> 11];   // scan blocks cover 2048 elements
}

__global__ void __launch_bounds__(256) partition_kernel(
    const int4* __restrict__ src4, const int4* __restrict__ dst4,
    const int* __restrict__ tmp, const int* __restrict__ boff,
    int* __restrict__ sorted, int n4, int nblk, int nb, int epb4) {
    __shared__ int cur[512];
    const int tid = threadIdx.x, blk = blockIdx.x;
    for (int b = tid; b < nb; b += 256) cur[b] = scanned_at(tmp, boff, b * nblk + blk);
    __syncthreads();
    const int beg4 = blk * epb4;
    const int end4 = min(n4, beg4 + epb4);
    for (int j = beg4 + tid; j < end4; j += 256) {
        int4 d = dst4[j];
        int4 s = src4[j];
        int p0 = atomicAdd(&cur[d.x >> 8], 1);
        int p1 = atomicAdd(&cur[d.y >> 8], 1);
        int p2 = atomicAdd(&cur[d.z >> 8], 1);
        int p3 = atomicAdd(&cur[d.w >> 8], 1);
        sorted[p0] = (s.x << 8) | (d.x & 255);
        sorted[p1] = (s.y << 8) | (d.y & 255);
        sorted[p2] = (s.z << 8) | (d.z & 255);
        sorted[p3] = (s.w << 8) | (d.w & 255);
    }
}

#define BKCAP 4096
__global__ void __launch_bounds__(256) bucket_build_kernel(
    const int* __restrict__ sorted, const int* __restrict__ tmp, const int* __restrict__ boff,
    int* __restrict__ row_ptr, float* __restrict__ dinv, int* __restrict__ col,
    int nblk, int n, int n_edges) {
    __shared__ int cnt[256], sc[256], cur[256];
    __shared__ int ecache[BKCAP];
    const int b = blockIdx.x, tid = threadIdx.x;
    const int base = scanned_at(tmp, boff, b * nblk);
    const int end  = (b == gridDim.x - 1) ? n_edges : scanned_at(tmp, boff, (b + 1) * nblk);
    const int m = end - base;
    const bool fits = (m <= BKCAP);

    cnt[tid] = 0;
    __syncthreads();
    if (fits) {
        for (int e = tid; e < m; e += 256) {
            int v = sorted[base + e];
            ecache[e] = v;
            atomicAdd(&cnt[v & 255], 1);
        }
    } else {
        for (int e = base + tid; e < end; e += 256)
            atomicAdd(&cnt[sorted[e] & 255], 1);
    }
    __syncthreads();

    sc[tid] = cnt[tid];
    __syncthreads();
#pragma unroll
    for (int off = 1; off < 256; off <<= 1) {
        int t = (tid >= off) ? sc[tid - off] : 0;
        __syncthreads();
        sc[tid] += t;
        __syncthreads();
    }
    int ex = sc[tid] - cnt[tid];
    cur[tid] = ex;

    int node = b * 256 + tid;
    if (node < n) {
        row_ptr[node] = base + ex;
        dinv[node] = rsqrtf((float)(cnt[tid] + 1));   // +1 = self-loop
    }
    if (b == gridDim.x - 1 && tid == 0) row_ptr[n] = n_edges;
    __syncthreads();

    if (fits) {
        for (int e = tid; e < m; e += 256) {
            int v = ecache[e];
            int lp = atomicAdd(&cur[v & 255], 1);
            col[base + lp] = v >> 8;
        }
    } else {
        for (int e = base + tid; e < end; e += 256) {
            int v = sorted[e];
            int lp = atomicAdd(&cur[v & 255], 1);
            col[base + lp] = v >> 8;
        }
    }
}

// ---------------- gemm1 (fp32 in, int16 out): hsq = q(dinv * X@W^T) ----------------
template<int K>
__global__ void __launch_bounds__(256) gemm_tile_kernel(
    const float* __restrict__ X, const float* __restrict__ W,
    const float* __restrict__ dinv, short* __restrict__ outq, float qs, int n) {
    constexpr int BK = 32;
    constexpr int NKB = K / BK;
    __shared__ float As[BK][132];
    __shared__ float Bs[BK][68];

    const int t = threadIdx.x;
    const int mbase = blockIdx.x * 128;
    const int tc = t & 15;
    const int tm = t >> 4;
    const int lr = t >> 3;
    const int k4 = (t & 7) * 4;

    float acc[8][4] = {};

    for (int kb = 0; kb < NKB; ++kb) {
        __syncthreads();
#pragma unroll
        for (int h = 0; h < 4; ++h) {
            int m = lr + h * 32;
            int node = mbase + m;
            float4 v = make_float4(0.f, 0.f, 0.f, 0.f);
            if (node < n)
                v = *reinterpret_cast<const float4*>(X + (size_t)node * K + kb * BK + k4);
            As[k4 + 0][m] = v.x; As[k4 + 1][m] = v.y;
            As[k4 + 2][m] = v.z; As[k4 + 3][m] = v.w;
        }
#pragma unroll
        for (int h = 0; h < 2; ++h) {
            int c = lr + h * 32;
            float4 wv = *reinterpret_cast<const float4*>(W + (size_t)c * K + kb * BK + k4);
            Bs[k4 + 0][c] = wv.x; Bs[k4 + 1][c] = wv.y;
            Bs[k4 + 2][c] = wv.z; Bs[k4 + 3][c] = wv.w;
        }
        __syncthreads();
#pragma unroll
        for (int k = 0; k < BK; ++k) {
            float4 a0 = *reinterpret_cast<const float4*>(&As[k][tm * 8]);
            float4 a1 = *reinterpret_cast<const float4*>(&As[k][tm * 8 + 4]);
            float4 b = *reinterpret_cast<const float4*>(&Bs[k][tc * 4]);
            acc[0][0] += a0.x * b.x; acc[0][1] += a0.x * b.y; acc[0][2] += a0.x * b.z; acc[0][3] += a0.x * b.w;
            acc[1][0] += a0.y * b.x; acc[1][1] += a0.y * b.y; acc[1][2] += a0.y * b.z; acc[1][3] += a0.y * b.w;
            acc[2][0] += a0.z * b.x; acc[2][1] += a0.z * b.y; acc[2][2] += a0.z * b.z; acc[2][3] += a0.z * b.w;
            acc[3][0] += a0.w * b.x; acc[3][1] += a0.w * b.y; acc[3][2] += a0.w * b.z; acc[3][3] += a0.w * b.w;
            acc[4][0] += a1.x * b.x; acc[4][1] += a1.x * b.y; acc[4][2] += a1.x * b.z; acc[4][3] += a1.x * b.w;
            acc[5][0] += a1.y * b.x; acc[5][1] += a1.y * b.y; acc[5][2] += a1.y * b.z; acc[5][3] += a1.y * b.w;
            acc[6][0] += a1.z * b.x; acc[6][1] += a1.z * b.y; acc[6][2] += a1.z * b.z; acc[6][3] += a1.z * b.w;
            acc[7][0] += a1.w * b.x; acc[7][1] += a1.w * b.y; acc[7][2] += a1.w * b.z; acc[7][3] += a1.w * b.w;
        }
    }

#pragma unroll
    for (int i = 0; i < 8; ++i) {
        int node = mbase + tm * 8 + i;
        if (node < n) {
            float s = dinv[node] * qs;
            int q0 = __float2int_rn(fminf(fmaxf(acc[i][0] * s, -32767.f), 32767.f));
            int q1 = __float2int_rn(fminf(fmaxf(acc[i][1] * s, -32767.f), 32767.f));
            int q2 = __float2int_rn(fminf(fmaxf(acc[i][2] * s, -32767.f), 32767.f));
            int q3 = __float2int_rn(fminf(fmaxf(acc[i][3] * s, -32767.f), 32767.f));
            int2 pk;
            pk.x = (q0 & 0xffff) | (q1 << 16);
            pk.y = (q2 & 0xffff) | (q3 << 16);
            *reinterpret_cast<int2*>(outq + (size_t)node * HID + tc * 4) = pk;
        }
    }
}

// ---------------- gemm2 (int16 in, int16 out), K=64: hs2q = q(dinv * h1 @ W2^T) ----------------
__global__ void __launch_bounds__(256) gemm_tile_q_kernel(
    const short* __restrict__ Xq, const float* __restrict__ W,
    const float* __restrict__ dinv, short* __restrict__ outq, float qs, int n) {
    constexpr int K = 64, BK = 32, NKB = 2;
    __shared__ float As[BK][132];
    __shared__ float Bs[BK][68];

    const int t = threadIdx.x;
    const int mbase = blockIdx.x * 128;
    const int tc = t & 15;
    const int tm = t >> 4;
    const int lr = t >> 3;
    const int k4 = (t & 7) * 4;

    float acc[8][4] = {};

    for (int kb = 0; kb < NKB; ++kb) {
        __syncthreads();
#pragma unroll
        for (int h = 0; h < 4; ++h) {
            int m = lr + h * 32;
            int node = mbase + m;
            int2 raw = make_int2(0, 0);
            if (node < n)
                raw = *reinterpret_cast<const int2*>(Xq + (size_t)node * K + kb * BK + k4);
            As[k4 + 0][m] = (float)((raw.x << 16) >> 16);
            As[k4 + 1][m] = (float)(raw.x >> 16);
            As[k4 + 2][m] = (float)((raw.y << 16) >> 16);
            As[k4 + 3][m] = (float)(raw.y >> 16);
        }
#pragma unroll
        for (int h = 0; h < 2; ++h) {
            int c = lr + h * 32;
            float4 wv = *reinterpret_cast<const float4*>(W + (size_t)c * K + kb * BK + k4);
            Bs[k4 + 0][c] = wv.x; Bs[k4 + 1][c] = wv.y;
            Bs[k4 + 2][c] = wv.z; Bs[k4 + 3][c] = wv.w;
        }
        __syncthreads();
#pragma unroll
        for (int k = 0; k < BK; ++k) {
            float4 a0 = *reinterpret_cast<const float4*>(&As[k][tm * 8]);
            float4 a1 = *reinterpret_cast<const float4*>(&As[k][tm * 8 + 4]);
            float4 b = *reinterpret_cast<const float4*>(&Bs[k][tc * 4]);
            acc[0][0] += a0.x * b.x; acc[0][1] += a0.x * b.y; acc[0][2] += a0.x * b.z; acc[0][3] += a0.x * b.w;
            acc[1][0] += a0.y * b.x; acc[1][1] += a0.y * b.y; acc[1][2] += a0.y * b.z; acc[1][3] += a0.y * b.w;
            acc[2][0] += a0.z * b.x; acc[2][1] += a0.z * b.y; acc[2][2] += a0.z * b.z; acc[2][3] += a0.z * b.w;
            acc[3][0] += a0.w * b.x; acc[3][1] += a0.w * b.y; acc[3][2] += a0.w * b.z; acc[3][3] += a0.w * b.w;
            acc[4][0] += a1.x * b.x; acc[4][1] += a1.x * b.y; acc[4][2] += a1.x * b.z; acc[4][3] += a1.x * b.w;
            acc[5][0] += a1.y * b.x; acc[5][1] += a1.y * b.y; acc[5][2] += a1.y * b.z; acc[5][3] += a1.y * b.w;
            acc[6][0] += a1.z * b.x; acc[6][1] += a1.z * b.y; acc[6][2] += a1.z * b.z; acc[6][3] += a1.z * b.w;
            acc[7][0] += a1.w * b.x; acc[7][1] += a1.w * b.y; acc[7][2] += a1.w * b.z; acc[7][3] += a1.w * b.w;
        }
    }

#pragma unroll
    for (int i = 0; i < 8; ++i) {
        int node = mbase + tm * 8 + i;
        if (node < n) {
            float s = dinv[node] * qs;   // qs = QS2/QH1 folded by caller
            int q0 = __float2int_rn(fminf(fmaxf(acc[i][0] * s, -32767.f), 32767.f));
            int q1 = __float2int_rn(fminf(fmaxf(acc[i][1] * s, -32767.f), 32767.f));
            int q2 = __float2int_rn(fminf(fmaxf(acc[i][2] * s, -32767.f), 32767.f));
            int q3 = __float2int_rn(fminf(fmaxf(acc[i][3] * s, -32767.f), 32767.f));
            int2 pk;
            pk.x = (q0 & 0xffff) | (q1 << 16);
            pk.y = (q2 & 0xffff) | (q3 << 16);
            *reinterpret_cast<int2*>(outq + (size_t)node * HID + tc * 4) = pk;
        }
    }
}

// ---------------- gather core, 8 lanes/node, int4 (16B) loads ----------------
// Row = 64 shorts = 8 x int4. Lane cl (0..7) owns channels [8cl, 8cl+8).
__device__ __forceinline__ void accum_q8(int acc[8], int4 v) {
    acc[0] += (v.x << 16) >> 16; acc[1] += v.x >> 16;
    acc[2] += (v.y << 16) >> 16; acc[3] += v.y >> 16;
    acc[4] += (v.z << 16) >> 16; acc[5] += v.z >> 16;
    acc[6] += (v.w << 16) >> 16; acc[7] += v.w >> 16;
}

__device__ __forceinline__ void gather_node_q8(
    const int4* __restrict__ hq4, const int* __restrict__ row_ptr, const int* __restrict__ col,
    int node, int cl, int acc[8]) {
    int beg = row_ptr[node];
    int end = row_ptr[node + 1];

    int4 sp = hq4[(size_t)node * 8 + cl];      // self-loop
    acc[0] = (sp.x << 16) >> 16; acc[1] = sp.x >> 16;
    acc[2] = (sp.y << 16) >> 16; acc[3] = sp.y >> 16;
    acc[4] = (sp.z << 16) >> 16; acc[5] = sp.z >> 16;
    acc[6] = (sp.w << 16) >> 16; acc[7] = sp.w >> 16;

    int e = beg;
    for (; e + 4 <= end; e += 4) {
        int s0 = col[e], s1 = col[e + 1], s2 = col[e + 2], s3 = col[e + 3];
        int4 v0 = hq4[(size_t)s0 * 8 + cl];
        int4 v1 = hq4[(size_t)s1 * 8 + cl];
        int4 v2 = hq4[(size_t)s2 * 8 + cl];
        int4 v3 = hq4[(size_t)s3 * 8 + cl];
        accum_q8(acc, v0);
        accum_q8(acc, v1);
        accum_q8(acc, v2);
        accum_q8(acc, v3);
    }
    for (; e < end; ++e)
        accum_q8(acc, hq4[(size_t)col[e] * 8 + cl]);
}

// full gather (layer 1): int16 in, int16 out; 8 nodes per wave, one pass
__global__ void __launch_bounds__(256) gather_kernel(
    const short* __restrict__ hsq, const int* __restrict__ row_ptr, const int* __restrict__ col,
    const float* __restrict__ dinv, const float* __restrict__ b, float qinv, float qh,
    short* __restrict__ outq, int n) {
    const int4* __restrict__ hq4 = (const int4*)hsq;
    const int lane = threadIdx.x & 63;
    const int sub = lane >> 3;        // node slot 0..7
    const int cl  = lane & 7;         // int4 index within row
    const int g = blockIdx.x * 4 + (threadIdx.x >> 6);

    int node = g * 8 + sub;
    if (node >= n) return;

    int acc[8];
    gather_node_q8(hq4, row_ptr, col, node, cl, acc);

    const float4* b4 = (const float4*)b;
    float4 bA = b4[cl * 2], bB = b4[cl * 2 + 1];
    float sq = dinv[node] * qinv;

    float r0 = fmaf((float)acc[0], sq, bA.x);
    float r1 = fmaf((float)acc[1], sq, bA.y);
    float r2 = fmaf((float)acc[2], sq, bA.z);
    float r3 = fmaf((float)acc[3], sq, bA.w);
    float r4 = fmaf((float)acc[4], sq, bB.x);
    float r5 = fmaf((float)acc[5], sq, bB.y);
    float r6 = fmaf((float)acc[6], sq, bB.z);
    float r7 = fmaf((float)acc[7], sq, bB.w);
    r0 = r0 > 0.f ? r0 : 0.f;  r1 = r1 > 0.f ? r1 : 0.f;
    r2 = r2 > 0.f ? r2 : 0.f;  r3 = r3 > 0.f ? r3 : 0.f;
    r4 = r4 > 0.f ? r4 : 0.f;  r5 = r5 > 0.f ? r5 : 0.f;
    r6 = r6 > 0.f ? r6 : 0.f;  r7 = r7 > 0.f ? r7 : 0.f;

    int q0 = __float2int_rn(fminf(r0 * qh, 32767.f));
    int q1 = __float2int_rn(fminf(r1 * qh, 32767.f));
    int q2 = __float2int_rn(fminf(r2 * qh, 32767.f));
    int q3 = __float2int_rn(fminf(r3 * qh, 32767.f));
    int q4 = __float2int_rn(fminf(r4 * qh, 32767.f));
    int q5 = __float2int_rn(fminf(r5 * qh, 32767.f));
    int q6 = __float2int_rn(fminf(r6 * qh, 32767.f));
    int q7 = __float2int_rn(fminf(r7 * qh, 32767.f));

    int4 pk;
    pk.x = (q0 & 0xffff) | (q1 << 16);
    pk.y = (q2 & 0xffff) | (q3 << 16);
    pk.z = (q4 & 0xffff) | (q5 << 16);
    pk.w = (q6 & 0xffff) | (q7 << 16);
    *((int4*)outq + (size_t)node * 8 + cl) = pk;
}

// fused sparse gather + prediction head: wave = 4 pairs; sub even=user, odd=movie
__global__ void __launch_bounds__(256) gather_final_kernel(
    const short* __restrict__ hsq, const int* __restrict__ row_ptr, const int* __restrict__ col,
    const int* __restrict__ users, const int* __restrict__ movies,
    const float* __restrict__ dinv, const float* __restrict__ b, float qinv,
    const float* __restrict__ fc_w, const float* __restrict__ fc_b,
    float* __restrict__ out, int batch) {
    const int4* __restrict__ hq4 = (const int4*)hsq;
    const int lane = threadIdx.x & 63;
    const int sub = lane >> 3;
    const int cl  = lane & 7;
    const int g = blockIdx.x * 4 + (threadIdx.x >> 6);

    int pair = g * 4 + (sub >> 1);
    int node = 0;   // dummy (valid memory) so all lanes participate in shuffles
    if (pair < batch) node = ((sub & 1) == 0) ? users[pair] : movies[pair];

    int acc[8];
    gather_node_q8(hq4, row_ptr, col, node, cl, acc);

    const float4* b4 = (const float4*)b;
    float4 bA = b4[cl * 2], bB = b4[cl * 2 + 1];
    float sq = dinv[node] * qinv;

    float r[8];
    r[0] = fmaf((float)acc[0], sq, bA.x);
    r[1] = fmaf((float)acc[1], sq, bA.y);
    r[2] = fmaf((float)acc[2], sq, bA.z);
    r[3] = fmaf((float)acc[3], sq, bA.w);
    r[4] = fmaf((float)acc[4], sq, bB.x);
    r[5] = fmaf((float)acc[5], sq, bB.y);
    r[6] = fmaf((float)acc[6], sq, bB.z);
    r[7] = fmaf((float)acc[7], sq, bB.w);
#pragma unroll
    for (int i = 0; i < 8; ++i) r[i] = r[i] > 0.f ? r[i] : 0.f;

    const float4* fw4 = (const float4*)fc_w;
    float4 fA = fw4[cl * 2], fB = fw4[cl * 2 + 1];
    float fw[8] = { fA.x, fA.y, fA.z, fA.w, fB.x, fB.y, fB.z, fB.w };

    // partner sub (u<->m) is lane ^ 8
    float s = 0.f;
#pragma unroll
    for (int i = 0; i < 8; ++i) {
        float p = __shfl_xor(r[i], 8, 64);
        s += r[i] * p * fw[i];
    }
    // reduce across the 8 cl lanes of this sub
#pragma unroll
    for (int off = 1; off < 8; off <<= 1)
        s += __shfl_xor(s, off, 64);

    // lanes 0,16,32,48 hold pairs g*4+0..3 (subs 0,2,4,6)
    if ((lane & 15) == 0) {
        int pr = g * 4 + (lane >> 4);
        if (pr < batch) out[pr] = s + fc_b[0];
    }
}

extern "C" void kernel_launch(void* const* d_in, const int* in_sizes, int n_in,
                              void* d_out, int out_size, void* d_ws, size_t ws_size,
                              hipStream_t stream) {
    const float* x     = (const float*)d_in[0];
    const int*   edge  = (const int*)d_in[1];   // [2][E]
    const int*   users = (const int*)d_in[2];
    const int*   movies= (const int*)d_in[3];
    const float* W1    = (const float*)d_in[4];
    const float* b1    = (const float*)d_in[5];
    const float* W2    = (const float*)d_in[6];
    const float* b2    = (const float*)d_in[7];
    const float* fc_w  = (const float*)d_in[8];
    const float* fc_b  = (const float*)d_in[9];
    float* out = (float*)d_out;

    const int IN_DIM = 128;
    const int n       = in_sizes[0] / IN_DIM;  // 100000
    const int n_edges = in_sizes[1] / 2;       // 1200000 (divisible by 4)
    const int batch   = in_sizes[2];           // 8192

    const int* esrc = edge;
    const int* edst = edge + n_edges;

    const int n4   = n_edges / 4;              // 300000
    const int NBLK = 512;                      // edge blocks for hist/partition
    const int EPB4 = (n4 + NBLK - 1) / NBLK;   // 586 int4 per block
    const int NB   = (n + 255) >> 8;           // 391 buckets
    const int HLEN = NB * NBLK;                // 200192
    const int SB   = (HLEN + 2047) / 2048;     // 98 scan blocks (<=128)

    char* ws = (char*)d_ws;
    size_t o = 0;
    auto alloc = [&](size_t bytes) { void* p = ws + o; o = (o + bytes + 255) & ~(size_t)255; return p; };
    int*   hist    = (int*)  alloc(sizeof(int) * HLEN);
    int*   tmp     = (int*)  alloc(sizeof(int) * HLEN);
    int*   bsum    = (int*)  alloc(sizeof(int) * 128);
    int*   boff    = (int*)  alloc(sizeof(int) * 128);
    int*   sorted  = (int*)  alloc(sizeof(int) * n_edges);   // packed (src<<8)|(dst&255)
    int*   col     = (int*)  alloc(sizeof(int) * n_edges);
    int*   row_ptr = (int*)  alloc(sizeof(int) * (n + 1));
    float* dinv    = (float*)alloc(sizeof(float) * n);
    short* Bq      = (short*)alloc(sizeof(short) * (size_t)n * HID);  // q(hs1) then q(hs2)
    short* Hq      = (short*)alloc(sizeof(short) * (size_t)n * HID);  // q(h1)

    // ---- atomic-free CSR build + norm (5 dispatches) ----
    hist_kernel<<<NBLK, 256, 0, stream>>>((const int4*)edst, hist, n4, NBLK, NB, EPB4);
    scan_partial_kernel<<<SB, 1024, 0, stream>>>(hist, tmp, bsum, HLEN);
    scan_sums_kernel<<<1, 128, 0, stream>>>(bsum, boff, SB);
    partition_kernel<<<NBLK, 256, 0, stream>>>((const int4*)esrc, (const int4*)edst,
                                               tmp, boff, sorted, n4, NBLK, NB, EPB4);
    bucket_build_kernel<<<NB, 256, 0, stream>>>(sorted, tmp, boff, row_ptr, dinv, col,
                                                NBLK, n, n_edges);

    const int gather_blocks = (n + 31) / 32;   // 8 nodes/wave, 4 waves/block -> 3125
    const int head_blocks = (batch + 15) / 16; // 4 pairs/wave, 4 waves/block -> 512

    // ---- layer 1 ----
    gemm_tile_kernel<128><<<(n + 127) / 128, 256, 0, stream>>>(x, W1, dinv, Bq, QS1, n);     // Bq = q(hs1)
    gather_kernel<<<gather_blocks, 256, 0, stream>>>(Bq, row_ptr, col, dinv, b1,
                                                     QINV1, QH1, Hq, n);                     // Hq = q(h1)

    // ---- layer 2 ----
    gemm_tile_q_kernel<<<(n + 127) / 128, 256, 0, stream>>>(Hq, W2, dinv, Bq, QS2 / QH1, n); // Bq = q(hs2)
    gather_final_kernel<<<head_blocks, 256, 0, stream>>>(Bq, row_ptr, col, users, movies,
                                                         dinv, b2, QINV2, fc_w, fc_b,
                                                         out, batch);                        // out = scores
}

// Round 19
// 129.403 us; speedup vs baseline: 2.9414x; 1.0264x over previous
//
#include <hip/hip_runtime.h>

#define HID 64

// int16 quantization scales
#define QS1   4096.0f   // hs1 range +-8
#define QINV1 (1.0f/4096.0f)
#define QH1   2048.0f   // h1 range +-16
#define QS2   2048.0f   // hs2 range +-16
#define QINV2 (1.0f/2048.0f)

// ================= atomic-free CSR build via bucket counting-sort (5 dispatches) ==========
__global__ void __launch_bounds__(256) hist_kernel(
    const int4* __restrict__ dst4, int* __restrict__ hist, int n4, int nblk, int nb, int epb4) {
    __shared__ int h[512];
    const int tid = threadIdx.x, blk = blockIdx.x;
    h[tid] = 0; h[tid + 256] = 0;
    __syncthreads();
    const int beg4 = blk * epb4;
    const int end4 = min(n4, beg4 + epb4);
    for (int j = beg4 + tid; j < end4; j += 256) {
        int4 d = dst4[j];
        atomicAdd(&h[d.x >> 8], 1);
        atomicAdd(&h[d.y >> 8], 1);
        atomicAdd(&h[d.z >> 8], 1);
        atomicAdd(&h[d.w >> 8], 1);
    }
    __syncthreads();
    for (int b = tid; b < nb; b += 256) hist[b * nblk + blk] = h[b];
}

__global__ void __launch_bounds__(1024) scan_partial_kernel(
    const int* __restrict__ in, int* __restrict__ tmp, int* __restrict__ bsum, int n) {
    __shared__ int sm[1024];
    const int tid = threadIdx.x;
    int i0 = blockIdx.x * 2048 + tid * 2;
    int a = (i0 < n) ? in[i0] : 0;
    int b = (i0 + 1 < n) ? in[i0 + 1] : 0;
    int v = a + b;
    sm[tid] = v;
    __syncthreads();
#pragma unroll
    for (int off = 1; off < 1024; off <<= 1) {
        int t = (tid >= off) ? sm[tid - off] : 0;
        __syncthreads();
        sm[tid] += t;
        __syncthreads();
    }
    int excl = sm[tid] - v;
    if (i0 < n) tmp[i0] = excl;
    if (i0 + 1 < n) tmp[i0 + 1] = excl + a;
    if (tid == 1023) bsum[blockIdx.x] = sm[1023];
}

__global__ void __launch_bounds__(128) scan_sums_kernel(
    const int* __restrict__ bsum, int* __restrict__ boff, int nb) {
    __shared__ int sm[128];
    const int tid = threadIdx.x;
    int v = (tid < nb) ? bsum[tid] : 0;
    sm[tid] = v;
    __syncthreads();
#pragma unroll
    for (int off = 1; off < 128; off <<= 1) {
        int t = (tid >= off) ? sm[tid - off] : 0;
        __syncthreads();
        sm[tid] += t;
        __syncthreads();
    }
    boff[tid] = sm[tid] - v;
}

__device__ __forceinline__ int scanned_at(const int* tmp, const int* boff, int idx) {
    return tmp[idx] + boff[idx >> 11];   // scan blocks cover 2048 elements
}

__global__ void __launch_bounds__(256) partition_kernel(
    const int4* __restrict__ src4, const int4* __restrict__ dst4,
    const int* __restrict__ tmp, const int* __restrict__ boff,
    int* __restrict__ sorted, int n4, int nblk, int nb, int epb4) {
    __shared__ int cur[512];
    const int tid = threadIdx.x, blk = blockIdx.x;
    for (int b = tid; b < nb; b += 256) cur[b] = scanned_at(tmp, boff, b * nblk + blk);
    __syncthreads();
    const int beg4 = blk * epb4;
    const int end4 = min(n4, beg4 + epb4);
    for (int j = beg4 + tid; j < end4; j += 256) {
        int4 d = dst4[j];
        int4 s = src4[j];
        int p0 = atomicAdd(&cur[d.x >> 8], 1);
        int p1 = atomicAdd(&cur[d.y >> 8], 1);
        int p2 = atomicAdd(&cur[d.z >> 8], 1);
        int p3 = atomicAdd(&cur[d.w >> 8], 1);
        sorted[p0] = (s.x << 8) | (d.x & 255);
        sorted[p1] = (s.y << 8) | (d.y & 255);
        sorted[p2] = (s.z << 8) | (d.z & 255);
        sorted[p3] = (s.w << 8) | (d.w & 255);
    }
}

#define BKCAP 4096
__global__ void __launch_bounds__(256) bucket_build_kernel(
    const int* __restrict__ sorted, const int* __restrict__ tmp, const int* __restrict__ boff,
    int* __restrict__ row_ptr, float* __restrict__ dinv, int* __restrict__ col,
    int nblk, int n, int n_edges) {
    __shared__ int cnt[256], sc[256], cur[256];
    __shared__ int ecache[BKCAP];
    const int b = blockIdx.x, tid = threadIdx.x;
    const int base = scanned_at(tmp, boff, b * nblk);
    const int end  = (b == gridDim.x - 1) ? n_edges : scanned_at(tmp, boff, (b + 1) * nblk);
    const int m = end - base;
    const bool fits = (m <= BKCAP);

    cnt[tid] = 0;
    __syncthreads();
    if (fits) {
        for (int e = tid; e < m; e += 256) {
            int v = sorted[base + e];
            ecache[e] = v;
            atomicAdd(&cnt[v & 255], 1);
        }
    } else {
        for (int e = base + tid; e < end; e += 256)
            atomicAdd(&cnt[sorted[e] & 255], 1);
    }
    __syncthreads();

    sc[tid] = cnt[tid];
    __syncthreads();
#pragma unroll
    for (int off = 1; off < 256; off <<= 1) {
        int t = (tid >= off) ? sc[tid - off] : 0;
        __syncthreads();
        sc[tid] += t;
        __syncthreads();
    }
    int ex = sc[tid] - cnt[tid];
    cur[tid] = ex;

    int node = b * 256 + tid;
    if (node < n) {
        row_ptr[node] = base + ex;
        dinv[node] = rsqrtf((float)(cnt[tid] + 1));   // +1 = self-loop
    }
    if (b == gridDim.x - 1 && tid == 0) row_ptr[n] = n_edges;
    __syncthreads();

    if (fits) {
        for (int e = tid; e < m; e += 256) {
            int v = ecache[e];
            int lp = atomicAdd(&cur[v & 255], 1);
            col[base + lp] = v >> 8;
        }
    } else {
        for (int e = base + tid; e < end; e += 256) {
            int v = sorted[e];
            int lp = atomicAdd(&cur[v & 255], 1);
            col[base + lp] = v >> 8;
        }
    }
}

// ---------------- gemm1 (fp32 in, int16 out), BM=BN=64, per-wave-kchunk staging ----------------
// Staging: wave w stages kchunks {w, w+4} for all 64 rows (m = t&63) -> LDS write bank =
// (16c + 4j + m) % 32 with m spanning 0..63 => exactly 2-way (free).
template<int K>
__global__ void __launch_bounds__(256) gemm_tile_kernel(
    const float* __restrict__ X, const float* __restrict__ W,
    const float* __restrict__ dinv, short* __restrict__ outq, float qs, int n) {
    constexpr int BK = 32;
    constexpr int NKB = K / BK;
    __shared__ float As[BK][68];   // As[k][m]
    __shared__ float Bs[BK][68];   // Bs[k][c]

    const int t = threadIdx.x;
    const int mbase = blockIdx.x * 64;
    const int tc = t & 15;
    const int tm = t >> 4;
    const int w  = t >> 6;        // wave id 0..3
    const int ml = t & 63;        // staged row / channel

    float acc[4][4] = {};

    for (int kb = 0; kb < NKB; ++kb) {
        __syncthreads();
#pragma unroll
        for (int h = 0; h < 2; ++h) {
            int c = w + h * 4;                      // kchunk 0..7
            int node = mbase + ml;
            float4 v = make_float4(0.f, 0.f, 0.f, 0.f);
            if (node < n)
                v = *reinterpret_cast<const float4*>(X + (size_t)node * K + kb * BK + c * 4);
            As[c * 4 + 0][ml] = v.x; As[c * 4 + 1][ml] = v.y;
            As[c * 4 + 2][ml] = v.z; As[c * 4 + 3][ml] = v.w;

            float4 wv = *reinterpret_cast<const float4*>(W + (size_t)ml * K + kb * BK + c * 4);
            Bs[c * 4 + 0][ml] = wv.x; Bs[c * 4 + 1][ml] = wv.y;
            Bs[c * 4 + 2][ml] = wv.z; Bs[c * 4 + 3][ml] = wv.w;
        }
        __syncthreads();
#pragma unroll
        for (int k = 0; k < BK; ++k) {
            float4 a = *reinterpret_cast<const float4*>(&As[k][tm * 4]);
            float4 b = *reinterpret_cast<const float4*>(&Bs[k][tc * 4]);
            acc[0][0] += a.x * b.x; acc[0][1] += a.x * b.y; acc[0][2] += a.x * b.z; acc[0][3] += a.x * b.w;
            acc[1][0] += a.y * b.x; acc[1][1] += a.y * b.y; acc[1][2] += a.y * b.z; acc[1][3] += a.y * b.w;
            acc[2][0] += a.z * b.x; acc[2][1] += a.z * b.y; acc[2][2] += a.z * b.z; acc[2][3] += a.z * b.w;
            acc[3][0] += a.w * b.x; acc[3][1] += a.w * b.y; acc[3][2] += a.w * b.z; acc[3][3] += a.w * b.w;
        }
    }

#pragma unroll
    for (int i = 0; i < 4; ++i) {
        int node = mbase + tm * 4 + i;
        if (node < n) {
            float s = dinv[node] * qs;
            int q0 = __float2int_rn(fminf(fmaxf(acc[i][0] * s, -32767.f), 32767.f));
            int q1 = __float2int_rn(fminf(fmaxf(acc[i][1] * s, -32767.f), 32767.f));
            int q2 = __float2int_rn(fminf(fmaxf(acc[i][2] * s, -32767.f), 32767.f));
            int q3 = __float2int_rn(fminf(fmaxf(acc[i][3] * s, -32767.f), 32767.f));
            int2 pk;
            pk.x = (q0 & 0xffff) | (q1 << 16);
            pk.y = (q2 & 0xffff) | (q3 << 16);
            *reinterpret_cast<int2*>(outq + (size_t)node * HID + tc * 4) = pk;
        }
    }
}

// ---------------- gemm2 (int16 in, int16 out), K=64, same BM=64 structure ----------------
__global__ void __launch_bounds__(256) gemm_tile_q_kernel(
    const short* __restrict__ Xq, const float* __restrict__ W,
    const float* __restrict__ dinv, short* __restrict__ outq, float qs, int n) {
    constexpr int K = 64, BK = 32, NKB = 2;
    __shared__ float As[BK][68];
    __shared__ float Bs[BK][68];

    const int t = threadIdx.x;
    const int mbase = blockIdx.x * 64;
    const int tc = t & 15;
    const int tm = t >> 4;
    const int w  = t >> 6;
    const int ml = t & 63;

    float acc[4][4] = {};

    for (int kb = 0; kb < NKB; ++kb) {
        __syncthreads();
#pragma unroll
        for (int h = 0; h < 2; ++h) {
            int c = w + h * 4;
            int node = mbase + ml;
            int2 raw = make_int2(0, 0);
            if (node < n)
                raw = *reinterpret_cast<const int2*>(Xq + (size_t)node * K + kb * BK + c * 4);
            As[c * 4 + 0][ml] = (float)((raw.x << 16) >> 16);
            As[c * 4 + 1][ml] = (float)(raw.x >> 16);
            As[c * 4 + 2][ml] = (float)((raw.y << 16) >> 16);
            As[c * 4 + 3][ml] = (float)(raw.y >> 16);

            float4 wv = *reinterpret_cast<const float4*>(W + (size_t)ml * K + kb * BK + c * 4);
            Bs[c * 4 + 0][ml] = wv.x; Bs[c * 4 + 1][ml] = wv.y;
            Bs[c * 4 + 2][ml] = wv.z; Bs[c * 4 + 3][ml] = wv.w;
        }
        __syncthreads();
#pragma unroll
        for (int k = 0; k < BK; ++k) {
            float4 a = *reinterpret_cast<const float4*>(&As[k][tm * 4]);
            float4 b = *reinterpret_cast<const float4*>(&Bs[k][tc * 4]);
            acc[0][0] += a.x * b.x; acc[0][1] += a.x * b.y; acc[0][2] += a.x * b.z; acc[0][3] += a.x * b.w;
            acc[1][0] += a.y * b.x; acc[1][1] += a.y * b.y; acc[1][2] += a.y * b.z; acc[1][3] += a.y * b.w;
            acc[2][0] += a.z * b.x; acc[2][1] += a.z * b.y; acc[2][2] += a.z * b.z; acc[2][3] += a.z * b.w;
            acc[3][0] += a.w * b.x; acc[3][1] += a.w * b.y; acc[3][2] += a.w * b.z; acc[3][3] += a.w * b.w;
        }
    }

#pragma unroll
    for (int i = 0; i < 4; ++i) {
        int node = mbase + tm * 4 + i;
        if (node < n) {
            float s = dinv[node] * qs;   // qs = QS2/QH1 folded by caller
            int q0 = __float2int_rn(fminf(fmaxf(acc[i][0] * s, -32767.f), 32767.f));
            int q1 = __float2int_rn(fminf(fmaxf(acc[i][1] * s, -32767.f), 32767.f));
            int q2 = __float2int_rn(fminf(fmaxf(acc[i][2] * s, -32767.f), 32767.f));
            int q3 = __float2int_rn(fminf(fmaxf(acc[i][3] * s, -32767.f), 32767.f));
            int2 pk;
            pk.x = (q0 & 0xffff) | (q1 << 16);
            pk.y = (q2 & 0xffff) | (q3 << 16);
            *reinterpret_cast<int2*>(outq + (size_t)node * HID + tc * 4) = pk;
        }
    }
}

// ---------------- gather core, 8 lanes/node, int4 (16B) loads ----------------
__device__ __forceinline__ void accum_q8(int acc[8], int4 v) {
    acc[0] += (v.x << 16) >> 16; acc[1] += v.x >> 16;
    acc[2] += (v.y << 16) >> 16; acc[3] += v.y >> 16;
    acc[4] += (v.z << 16) >> 16; acc[5] += v.z >> 16;
    acc[6] += (v.w << 16) >> 16; acc[7] += v.w >> 16;
}

__device__ __forceinline__ void gather_node_q8(
    const int4* __restrict__ hq4, const int* __restrict__ row_ptr, const int* __restrict__ col,
    int node, int cl, int acc[8]) {
    int beg = row_ptr[node];
    int end = row_ptr[node + 1];

    int4 sp = hq4[(size_t)node * 8 + cl];      // self-loop
    acc[0] = (sp.x << 16) >> 16; acc[1] = sp.x >> 16;
    acc[2] = (sp.y << 16) >> 16; acc[3] = sp.y >> 16;
    acc[4] = (sp.z << 16) >> 16; acc[5] = sp.z >> 16;
    acc[6] = (sp.w << 16) >> 16; acc[7] = sp.w >> 16;

    int e = beg;
    for (; e + 4 <= end; e += 4) {
        int s0 = col[e], s1 = col[e + 1], s2 = col[e + 2], s3 = col[e + 3];
        int4 v0 = hq4[(size_t)s0 * 8 + cl];
        int4 v1 = hq4[(size_t)s1 * 8 + cl];
        int4 v2 = hq4[(size_t)s2 * 8 + cl];
        int4 v3 = hq4[(size_t)s3 * 8 + cl];
        accum_q8(acc, v0);
        accum_q8(acc, v1);
        accum_q8(acc, v2);
        accum_q8(acc, v3);
    }
    for (; e < end; ++e)
        accum_q8(acc, hq4[(size_t)col[e] * 8 + cl]);
}

// full gather (layer 1): int16 in, int16 out; 8 nodes per wave, one pass
__global__ void __launch_bounds__(256) gather_kernel(
    const short* __restrict__ hsq, const int* __restrict__ row_ptr, const int* __restrict__ col,
    const float* __restrict__ dinv, const float* __restrict__ b, float qinv, float qh,
    short* __restrict__ outq, int n) {
    const int4* __restrict__ hq4 = (const int4*)hsq;
    const int lane = threadIdx.x & 63;
    const int sub = lane >> 3;        // node slot 0..7
    const int cl  = lane & 7;         // int4 index within row
    const int g = blockIdx.x * 4 + (threadIdx.x >> 6);

    int node = g * 8 + sub;
    if (node >= n) return;

    int acc[8];
    gather_node_q8(hq4, row_ptr, col, node, cl, acc);

    const float4* b4 = (const float4*)b;
    float4 bA = b4[cl * 2], bB = b4[cl * 2 + 1];
    float sq = dinv[node] * qinv;

    float r0 = fmaf((float)acc[0], sq, bA.x);
    float r1 = fmaf((float)acc[1], sq, bA.y);
    float r2 = fmaf((float)acc[2], sq, bA.z);
    float r3 = fmaf((float)acc[3], sq, bA.w);
    float r4 = fmaf((float)acc[4], sq, bB.x);
    float r5 = fmaf((float)acc[5], sq, bB.y);
    float r6 = fmaf((float)acc[6], sq, bB.z);
    float r7 = fmaf((float)acc[7], sq, bB.w);
    r0 = r0 > 0.f ? r0 : 0.f;  r1 = r1 > 0.f ? r1 : 0.f;
    r2 = r2 > 0.f ? r2 : 0.f;  r3 = r3 > 0.f ? r3 : 0.f;
    r4 = r4 > 0.f ? r4 : 0.f;  r5 = r5 > 0.f ? r5 : 0.f;
    r6 = r6 > 0.f ? r6 : 0.f;  r7 = r7 > 0.f ? r7 : 0.f;

    int q0 = __float2int_rn(fminf(r0 * qh, 32767.f));
    int q1 = __float2int_rn(fminf(r1 * qh, 32767.f));
    int q2 = __float2int_rn(fminf(r2 * qh, 32767.f));
    int q3 = __float2int_rn(fminf(r3 * qh, 32767.f));
    int q4 = __float2int_rn(fminf(r4 * qh, 32767.f));
    int q5 = __float2int_rn(fminf(r5 * qh, 32767.f));
    int q6 = __float2int_rn(fminf(r6 * qh, 32767.f));
    int q7 = __float2int_rn(fminf(r7 * qh, 32767.f));

    int4 pk;
    pk.x = (q0 & 0xffff) | (q1 << 16);
    pk.y = (q2 & 0xffff) | (q3 << 16);
    pk.z = (q4 & 0xffff) | (q5 << 16);
    pk.w = (q6 & 0xffff) | (q7 << 16);
    *((int4*)outq + (size_t)node * 8 + cl) = pk;
}

// fused sparse gather + prediction head: wave = 4 pairs; sub even=user, odd=movie
__global__ void __launch_bounds__(256) gather_final_kernel(
    const short* __restrict__ hsq, const int* __restrict__ row_ptr, const int* __restrict__ col,
    const int* __restrict__ users, const int* __restrict__ movies,
    const float* __restrict__ dinv, const float* __restrict__ b, float qinv,
    const float* __restrict__ fc_w, const float* __restrict__ fc_b,
    float* __restrict__ out, int batch) {
    const int4* __restrict__ hq4 = (const int4*)hsq;
    const int lane = threadIdx.x & 63;
    const int sub = lane >> 3;
    const int cl  = lane & 7;
    const int g = blockIdx.x * 4 + (threadIdx.x >> 6);

    int pair = g * 4 + (sub >> 1);
    int node = 0;   // dummy (valid memory) so all lanes participate in shuffles
    if (pair < batch) node = ((sub & 1) == 0) ? users[pair] : movies[pair];

    int acc[8];
    gather_node_q8(hq4, row_ptr, col, node, cl, acc);

    const float4* b4 = (const float4*)b;
    float4 bA = b4[cl * 2], bB = b4[cl * 2 + 1];
    float sq = dinv[node] * qinv;

    float r[8];
    r[0] = fmaf((float)acc[0], sq, bA.x);
    r[1] = fmaf((float)acc[1], sq, bA.y);
    r[2] = fmaf((float)acc[2], sq, bA.z);
    r[3] = fmaf((float)acc[3], sq, bA.w);
    r[4] = fmaf((float)acc[4], sq, bB.x);
    r[5] = fmaf((float)acc[5], sq, bB.y);
    r[6] = fmaf((float)acc[6], sq, bB.z);
    r[7] = fmaf((float)acc[7], sq, bB.w);
#pragma unroll
    for (int i = 0; i < 8; ++i) r[i] = r[i] > 0.f ? r[i] : 0.f;

    const float4* fw4 = (const float4*)fc_w;
    float4 fA = fw4[cl * 2], fB = fw4[cl * 2 + 1];
    float fw[8] = { fA.x, fA.y, fA.z, fA.w, fB.x, fB.y, fB.z, fB.w };

    // partner sub (u<->m) is lane ^ 8
    float s = 0.f;
#pragma unroll
    for (int i = 0; i < 8; ++i) {
        float p = __shfl_xor(r[i], 8, 64);
        s += r[i] * p * fw[i];
    }
    // reduce across the 8 cl lanes of this sub
#pragma unroll
    for (int off = 1; off < 8; off <<= 1)
        s += __shfl_xor(s, off, 64);

    // lanes 0,16,32,48 hold pairs g*4+0..3 (subs 0,2,4,6)
    if ((lane & 15) == 0) {
        int pr = g * 4 + (lane >> 4);
        if (pr < batch) out[pr] = s + fc_b[0];
    }
}

extern "C" void kernel_launch(void* const* d_in, const int* in_sizes, int n_in,
                              void* d_out, int out_size, void* d_ws, size_t ws_size,
                              hipStream_t stream) {
    const float* x     = (const float*)d_in[0];
    const int*   edge  = (const int*)d_in[1];   // [2][E]
    const int*   users = (const int*)d_in[2];
    const int*   movies= (const int*)d_in[3];
    const float* W1    = (const float*)d_in[4];
    const float* b1    = (const float*)d_in[5];
    const float* W2    = (const float*)d_in[6];
    const float* b2    = (const float*)d_in[7];
    const float* fc_w  = (const float*)d_in[8];
    const float* fc_b  = (const float*)d_in[9];
    float* out = (float*)d_out;

    const int IN_DIM = 128;
    const int n       = in_sizes[0] / IN_DIM;  // 100000
    const int n_edges = in_sizes[1] / 2;       // 1200000 (divisible by 4)
    const int batch   = in_sizes[2];           // 8192

    const int* esrc = edge;
    const int* edst = edge + n_edges;

    const int n4   = n_edges / 4;              // 300000
    const int NBLK = 512;                      // edge blocks for hist/partition
    const int EPB4 = (n4 + NBLK - 1) / NBLK;   // 586 int4 per block
    const int NB   = (n + 255) >> 8;           // 391 buckets
    const int HLEN = NB * NBLK;                // 200192
    const int SB   = (HLEN + 2047) / 2048;     // 98 scan blocks (<=128)

    char* ws = (char*)d_ws;
    size_t o = 0;
    auto alloc = [&](size_t bytes) { void* p = ws + o; o = (o + bytes + 255) & ~(size_t)255; return p; };
    int*   hist    = (int*)  alloc(sizeof(int) * HLEN);
    int*   tmp     = (int*)  alloc(sizeof(int) * HLEN);
    int*   bsum    = (int*)  alloc(sizeof(int) * 128);
    int*   boff    = (int*)  alloc(sizeof(int) * 128);
    int*   sorted  = (int*)  alloc(sizeof(int) * n_edges);   // packed (src<<8)|(dst&255)
    int*   col     = (int*)  alloc(sizeof(int) * n_edges);
    int*   row_ptr = (int*)  alloc(sizeof(int) * (n + 1));
    float* dinv    = (float*)alloc(sizeof(float) * n);
    short* Bq      = (short*)alloc(sizeof(short) * (size_t)n * HID);  // q(hs1) then q(hs2)
    short* Hq      = (short*)alloc(sizeof(short) * (size_t)n * HID);  // q(h1)

    // ---- atomic-free CSR build + norm (5 dispatches) ----
    hist_kernel<<<NBLK, 256, 0, stream>>>((const int4*)edst, hist, n4, NBLK, NB, EPB4);
    scan_partial_kernel<<<SB, 1024, 0, stream>>>(hist, tmp, bsum, HLEN);
    scan_sums_kernel<<<1, 128, 0, stream>>>(bsum, boff, SB);
    partition_kernel<<<NBLK, 256, 0, stream>>>((const int4*)esrc, (const int4*)edst,
                                               tmp, boff, sorted, n4, NBLK, NB, EPB4);
    bucket_build_kernel<<<NB, 256, 0, stream>>>(sorted, tmp, boff, row_ptr, dinv, col,
                                                NBLK, n, n_edges);

    const int gemm_blocks = (n + 63) / 64;     // 1563 (~6.1 blocks/CU)
    const int gather_blocks = (n + 31) / 32;   // 8 nodes/wave, 4 waves/block -> 3125
    const int head_blocks = (batch + 15) / 16; // 4 pairs/wave, 4 waves/block -> 512

    // ---- layer 1 ----
    gemm_tile_kernel<128><<<gemm_blocks, 256, 0, stream>>>(x, W1, dinv, Bq, QS1, n);      // Bq = q(hs1)
    gather_kernel<<<gather_blocks, 256, 0, stream>>>(Bq, row_ptr, col, dinv, b1,
                                                     QINV1, QH1, Hq, n);                  // Hq = q(h1)

    // ---- layer 2 ----
    gemm_tile_q_kernel<<<gemm_blocks, 256, 0, stream>>>(Hq, W2, dinv, Bq, QS2 / QH1, n);  // Bq = q(hs2)
    gather_final_kernel<<<head_blocks, 256, 0, stream>>>(Bq, row_ptr, col, users, movies,
                                                         dinv, b2, QINV2, fc_w, fc_b,
                                                         out, batch);                     // out = scores
}

// Round 20
// 129.274 us; speedup vs baseline: 2.9443x; 1.0010x over previous
//
#include <hip/hip_runtime.h>

#define HID 64

// int16 quantization scales
#define QS1   4096.0f   // hs1 range +-8
#define QINV1 (1.0f/4096.0f)
#define QH1   2048.0f   // h1 range +-16
#define QS2   2048.0f   // hs2 range +-16
#define QINV2 (1.0f/2048.0f)

// ================= atomic-free CSR build via bucket counting-sort (4 dispatches) ==========
// Buckets of 256 consecutive dst nodes; NB = ceil(n/256). NBLK=512 edge blocks.
// hist/tmp layout: [bucket][block], bucket-major. Block-offset scan (over the <=128
// scan-block sums) is computed INLINE in partition/bucket_build (no scan_sums dispatch).
// sorted entries packed: (src << 8) | (dst & 255)   (src < 2^17 fits in 25 bits)

__global__ void __launch_bounds__(256) hist_kernel(
    const int4* __restrict__ dst4, int* __restrict__ hist, int n4, int nblk, int nb, int epb4) {
    __shared__ int h[512];
    const int tid = threadIdx.x, blk = blockIdx.x;
    h[tid] = 0; h[tid + 256] = 0;
    __syncthreads();
    const int beg4 = blk * epb4;
    const int end4 = min(n4, beg4 + epb4);
    for (int j = beg4 + tid; j < end4; j += 256) {
        int4 d = dst4[j];
        atomicAdd(&h[d.x >> 8], 1);
        atomicAdd(&h[d.y >> 8], 1);
        atomicAdd(&h[d.z >> 8], 1);
        atomicAdd(&h[d.w >> 8], 1);
    }
    __syncthreads();
    for (int b = tid; b < nb; b += 256) hist[b * nblk + blk] = h[b];
}

__global__ void __launch_bounds__(1024) scan_partial_kernel(
    const int* __restrict__ in, int* __restrict__ tmp, int* __restrict__ bsum, int n) {
    __shared__ int sm[1024];
    const int tid = threadIdx.x;
    int i0 = blockIdx.x * 2048 + tid * 2;
    int a = (i0 < n) ? in[i0] : 0;
    int b = (i0 + 1 < n) ? in[i0 + 1] : 0;
    int v = a + b;
    sm[tid] = v;
    __syncthreads();
#pragma unroll
    for (int off = 1; off < 1024; off <<= 1) {
        int t = (tid >= off) ? sm[tid - off] : 0;
        __syncthreads();
        sm[tid] += t;
        __syncthreads();
    }
    int excl = sm[tid] - v;
    if (i0 < n) tmp[i0] = excl;
    if (i0 + 1 < n) tmp[i0 + 1] = excl + a;
    if (tid == 1023) bsum[blockIdx.x] = sm[1023];
}

// inline LDS scan of the scan-block sums (sb <= 128): sboff[i] = inclusive prefix
__device__ __forceinline__ void inline_boff_scan(const int* __restrict__ bsum,
                                                 int* __restrict__ sboff, int sb, int tid) {
    if (tid < 128) sboff[tid] = (tid < sb) ? bsum[tid] : 0;
    __syncthreads();
#pragma unroll
    for (int off = 1; off < 128; off <<= 1) {
        int t = (tid >= off && tid < 128) ? sboff[tid - off] : 0;
        __syncthreads();
        if (tid < 128) sboff[tid] += t;
        __syncthreads();
    }
}

__device__ __forceinline__ int scanned_at_lds(const int* __restrict__ tmp,
                                              const int* __restrict__ sboff, int idx) {
    int sblk = idx >> 11;                       // scan blocks cover 2048 elements
    int off = (sblk == 0) ? 0 : sboff[sblk - 1];  // exclusive via shift
    return tmp[idx] + off;
}

__global__ void __launch_bounds__(256) partition_kernel(
    const int4* __restrict__ src4, const int4* __restrict__ dst4,
    const int* __restrict__ tmp, const int* __restrict__ bsum,
    int* __restrict__ sorted, int n4, int nblk, int nb, int epb4, int sb) {
    __shared__ int cur[512];
    __shared__ int sboff[128];
    const int tid = threadIdx.x, blk = blockIdx.x;

    inline_boff_scan(bsum, sboff, sb, tid);

    for (int b = tid; b < nb; b += 256) cur[b] = scanned_at_lds(tmp, sboff, b * nblk + blk);
    __syncthreads();
    const int beg4 = blk * epb4;
    const int end4 = min(n4, beg4 + epb4);
    for (int j = beg4 + tid; j < end4; j += 256) {
        int4 d = dst4[j];
        int4 s = src4[j];
        int p0 = atomicAdd(&cur[d.x >> 8], 1);
        int p1 = atomicAdd(&cur[d.y >> 8], 1);
        int p2 = atomicAdd(&cur[d.z >> 8], 1);
        int p3 = atomicAdd(&cur[d.w >> 8], 1);
        sorted[p0] = (s.x << 8) | (d.x & 255);
        sorted[p1] = (s.y << 8) | (d.y & 255);
        sorted[p2] = (s.z << 8) | (d.z & 255);
        sorted[p3] = (s.w << 8) | (d.w & 255);
    }
}

#define BKCAP 4096
__global__ void __launch_bounds__(256) bucket_build_kernel(
    const int* __restrict__ sorted, const int* __restrict__ tmp, const int* __restrict__ bsum,
    int* __restrict__ row_ptr, float* __restrict__ dinv, int* __restrict__ col,
    int nblk, int n, int n_edges, int sb) {
    __shared__ int cnt[256], sc[256], cur[256];
    __shared__ int sboff[128];
    __shared__ int ecache[BKCAP];
    const int b = blockIdx.x, tid = threadIdx.x;

    inline_boff_scan(bsum, sboff, sb, tid);

    const int base = scanned_at_lds(tmp, sboff, b * nblk);
    const int end  = (b == gridDim.x - 1) ? n_edges : scanned_at_lds(tmp, sboff, (b + 1) * nblk);
    const int m = end - base;
    const bool fits = (m <= BKCAP);

    cnt[tid] = 0;
    __syncthreads();
    if (fits) {
        for (int e = tid; e < m; e += 256) {
            int v = sorted[base + e];
            ecache[e] = v;
            atomicAdd(&cnt[v & 255], 1);
        }
    } else {
        for (int e = base + tid; e < end; e += 256)
            atomicAdd(&cnt[sorted[e] & 255], 1);
    }
    __syncthreads();

    sc[tid] = cnt[tid];
    __syncthreads();
#pragma unroll
    for (int off = 1; off < 256; off <<= 1) {
        int t = (tid >= off) ? sc[tid - off] : 0;
        __syncthreads();
        sc[tid] += t;
        __syncthreads();
    }
    int ex = sc[tid] - cnt[tid];
    cur[tid] = ex;

    int node = b * 256 + tid;
    if (node < n) {
        row_ptr[node] = base + ex;
        dinv[node] = rsqrtf((float)(cnt[tid] + 1));   // +1 = self-loop
    }
    if (b == gridDim.x - 1 && tid == 0) row_ptr[n] = n_edges;
    __syncthreads();

    if (fits) {
        for (int e = tid; e < m; e += 256) {
            int v = ecache[e];
            int lp = atomicAdd(&cur[v & 255], 1);
            col[base + lp] = v >> 8;
        }
    } else {
        for (int e = base + tid; e < end; e += 256) {
            int v = sorted[e];
            int lp = atomicAdd(&cur[v & 255], 1);
            col[base + lp] = v >> 8;
        }
    }
}

// ---------------- gemm1 (fp32 in, int16 out), BM=BN=64, per-wave-kchunk staging ----------------
template<int K>
__global__ void __launch_bounds__(256) gemm_tile_kernel(
    const float* __restrict__ X, const float* __restrict__ W,
    const float* __restrict__ dinv, short* __restrict__ outq, float qs, int n) {
    constexpr int BK = 32;
    constexpr int NKB = K / BK;
    __shared__ float As[BK][68];   // As[k][m]
    __shared__ float Bs[BK][68];   // Bs[k][c]

    const int t = threadIdx.x;
    const int mbase = blockIdx.x * 64;
    const int tc = t & 15;
    const int tm = t >> 4;
    const int w  = t >> 6;        // wave id 0..3
    const int ml = t & 63;        // staged row / channel

    float acc[4][4] = {};

    for (int kb = 0; kb < NKB; ++kb) {
        __syncthreads();
#pragma unroll
        for (int h = 0; h < 2; ++h) {
            int c = w + h * 4;                      // kchunk 0..7
            int node = mbase + ml;
            float4 v = make_float4(0.f, 0.f, 0.f, 0.f);
            if (node < n)
                v = *reinterpret_cast<const float4*>(X + (size_t)node * K + kb * BK + c * 4);
            As[c * 4 + 0][ml] = v.x; As[c * 4 + 1][ml] = v.y;
            As[c * 4 + 2][ml] = v.z; As[c * 4 + 3][ml] = v.w;

            float4 wv = *reinterpret_cast<const float4*>(W + (size_t)ml * K + kb * BK + c * 4);
            Bs[c * 4 + 0][ml] = wv.x; Bs[c * 4 + 1][ml] = wv.y;
            Bs[c * 4 + 2][ml] = wv.z; Bs[c * 4 + 3][ml] = wv.w;
        }
        __syncthreads();
#pragma unroll
        for (int k = 0; k < BK; ++k) {
            float4 a = *reinterpret_cast<const float4*>(&As[k][tm * 4]);
            float4 b = *reinterpret_cast<const float4*>(&Bs[k][tc * 4]);
            acc[0][0] += a.x * b.x; acc[0][1] += a.x * b.y; acc[0][2] += a.x * b.z; acc[0][3] += a.x * b.w;
            acc[1][0] += a.y * b.x; acc[1][1] += a.y * b.y; acc[1][2] += a.y * b.z; acc[1][3] += a.y * b.w;
            acc[2][0] += a.z * b.x; acc[2][1] += a.z * b.y; acc[2][2] += a.z * b.z; acc[2][3] += a.z * b.w;
            acc[3][0] += a.w * b.x; acc[3][1] += a.w * b.y; acc[3][2] += a.w * b.z; acc[3][3] += a.w * b.w;
        }
    }

#pragma unroll
    for (int i = 0; i < 4; ++i) {
        int node = mbase + tm * 4 + i;
        if (node < n) {
            float s = dinv[node] * qs;
            int q0 = __float2int_rn(fminf(fmaxf(acc[i][0] * s, -32767.f), 32767.f));
            int q1 = __float2int_rn(fminf(fmaxf(acc[i][1] * s, -32767.f), 32767.f));
            int q2 = __float2int_rn(fminf(fmaxf(acc[i][2] * s, -32767.f), 32767.f));
            int q3 = __float2int_rn(fminf(fmaxf(acc[i][3] * s, -32767.f), 32767.f));
            int2 pk;
            pk.x = (q0 & 0xffff) | (q1 << 16);
            pk.y = (q2 & 0xffff) | (q3 << 16);
            *reinterpret_cast<int2*>(outq + (size_t)node * HID + tc * 4) = pk;
        }
    }
}

// ---------------- gemm2 (int16 in, int16 out), K=64, same BM=64 structure ----------------
__global__ void __launch_bounds__(256) gemm_tile_q_kernel(
    const short* __restrict__ Xq, const float* __restrict__ W,
    const float* __restrict__ dinv, short* __restrict__ outq, float qs, int n) {
    constexpr int K = 64, BK = 32, NKB = 2;
    __shared__ float As[BK][68];
    __shared__ float Bs[BK][68];

    const int t = threadIdx.x;
    const int mbase = blockIdx.x * 64;
    const int tc = t & 15;
    const int tm = t >> 4;
    const int w  = t >> 6;
    const int ml = t & 63;

    float acc[4][4] = {};

    for (int kb = 0; kb < NKB; ++kb) {
        __syncthreads();
#pragma unroll
        for (int h = 0; h < 2; ++h) {
            int c = w + h * 4;
            int node = mbase + ml;
            int2 raw = make_int2(0, 0);
            if (node < n)
                raw = *reinterpret_cast<const int2*>(Xq + (size_t)node * K + kb * BK + c * 4);
            As[c * 4 + 0][ml] = (float)((raw.x << 16) >> 16);
            As[c * 4 + 1][ml] = (float)(raw.x >> 16);
            As[c * 4 + 2][ml] = (float)((raw.y << 16) >> 16);
            As[c * 4 + 3][ml] = (float)(raw.y >> 16);

            float4 wv = *reinterpret_cast<const float4*>(W + (size_t)ml * K + kb * BK + c * 4);
            Bs[c * 4 + 0][ml] = wv.x; Bs[c * 4 + 1][ml] = wv.y;
            Bs[c * 4 + 2][ml] = wv.z; Bs[c * 4 + 3][ml] = wv.w;
        }
        __syncthreads();
#pragma unroll
        for (int k = 0; k < BK; ++k) {
            float4 a = *reinterpret_cast<const float4*>(&As[k][tm * 4]);
            float4 b = *reinterpret_cast<const float4*>(&Bs[k][tc * 4]);
            acc[0][0] += a.x * b.x; acc[0][1] += a.x * b.y; acc[0][2] += a.x * b.z; acc[0][3] += a.x * b.w;
            acc[1][0] += a.y * b.x; acc[1][1] += a.y * b.y; acc[1][2] += a.y * b.z; acc[1][3] += a.y * b.w;
            acc[2][0] += a.z * b.x; acc[2][1] += a.z * b.y; acc[2][2] += a.z * b.z; acc[2][3] += a.z * b.w;
            acc[3][0] += a.w * b.x; acc[3][1] += a.w * b.y; acc[3][2] += a.w * b.z; acc[3][3] += a.w * b.w;
        }
    }

#pragma unroll
    for (int i = 0; i < 4; ++i) {
        int node = mbase + tm * 4 + i;
        if (node < n) {
            float s = dinv[node] * qs;   // qs = QS2/QH1 folded by caller
            int q0 = __float2int_rn(fminf(fmaxf(acc[i][0] * s, -32767.f), 32767.f));
            int q1 = __float2int_rn(fminf(fmaxf(acc[i][1] * s, -32767.f), 32767.f));
            int q2 = __float2int_rn(fminf(fmaxf(acc[i][2] * s, -32767.f), 32767.f));
            int q3 = __float2int_rn(fminf(fmaxf(acc[i][3] * s, -32767.f), 32767.f));
            int2 pk;
            pk.x = (q0 & 0xffff) | (q1 << 16);
            pk.y = (q2 & 0xffff) | (q3 << 16);
            *reinterpret_cast<int2*>(outq + (size_t)node * HID + tc * 4) = pk;
        }
    }
}

// ---------------- gather core, 8 lanes/node, int4 (16B) loads ----------------
__device__ __forceinline__ void accum_q8(int acc[8], int4 v) {
    acc[0] += (v.x << 16) >> 16; acc[1] += v.x >> 16;
    acc[2] += (v.y << 16) >> 16; acc[3] += v.y >> 16;
    acc[4] += (v.z << 16) >> 16; acc[5] += v.z >> 16;
    acc[6] += (v.w << 16) >> 16; acc[7] += v.w >> 16;
}

__device__ __forceinline__ void gather_node_q8(
    const int4* __restrict__ hq4, const int* __restrict__ row_ptr, const int* __restrict__ col,
    int node, int cl, int acc[8]) {
    int beg = row_ptr[node];
    int end = row_ptr[node + 1];

    int4 sp = hq4[(size_t)node * 8 + cl];      // self-loop
    acc[0] = (sp.x << 16) >> 16; acc[1] = sp.x >> 16;
    acc[2] = (sp.y << 16) >> 16; acc[3] = sp.y >> 16;
    acc[4] = (sp.z << 16) >> 16; acc[5] = sp.z >> 16;
    acc[6] = (sp.w << 16) >> 16; acc[7] = sp.w >> 16;

    int e = beg;
    for (; e + 4 <= end; e += 4) {
        int s0 = col[e], s1 = col[e + 1], s2 = col[e + 2], s3 = col[e + 3];
        int4 v0 = hq4[(size_t)s0 * 8 + cl];
        int4 v1 = hq4[(size_t)s1 * 8 + cl];
        int4 v2 = hq4[(size_t)s2 * 8 + cl];
        int4 v3 = hq4[(size_t)s3 * 8 + cl];
        accum_q8(acc, v0);
        accum_q8(acc, v1);
        accum_q8(acc, v2);
        accum_q8(acc, v3);
    }
    for (; e < end; ++e)
        accum_q8(acc, hq4[(size_t)col[e] * 8 + cl]);
}

// full gather (layer 1): int16 in, int16 out; 8 nodes per wave, one pass
__global__ void __launch_bounds__(256) gather_kernel(
    const short* __restrict__ hsq, const int* __restrict__ row_ptr, const int* __restrict__ col,
    const float* __restrict__ dinv, const float* __restrict__ b, float qinv, float qh,
    short* __restrict__ outq, int n) {
    const int4* __restrict__ hq4 = (const int4*)hsq;
    const int lane = threadIdx.x & 63;
    const int sub = lane >> 3;        // node slot 0..7
    const int cl  = lane & 7;         // int4 index within row
    const int g = blockIdx.x * 4 + (threadIdx.x >> 6);

    int node = g * 8 + sub;
    if (node >= n) return;

    int acc[8];
    gather_node_q8(hq4, row_ptr, col, node, cl, acc);

    const float4* b4 = (const float4*)b;
    float4 bA = b4[cl * 2], bB = b4[cl * 2 + 1];
    float sq = dinv[node] * qinv;

    float r0 = fmaf((float)acc[0], sq, bA.x);
    float r1 = fmaf((float)acc[1], sq, bA.y);
    float r2 = fmaf((float)acc[2], sq, bA.z);
    float r3 = fmaf((float)acc[3], sq, bA.w);
    float r4 = fmaf((float)acc[4], sq, bB.x);
    float r5 = fmaf((float)acc[5], sq, bB.y);
    float r6 = fmaf((float)acc[6], sq, bB.z);
    float r7 = fmaf((float)acc[7], sq, bB.w);
    r0 = r0 > 0.f ? r0 : 0.f;  r1 = r1 > 0.f ? r1 : 0.f;
    r2 = r2 > 0.f ? r2 : 0.f;  r3 = r3 > 0.f ? r3 : 0.f;
    r4 = r4 > 0.f ? r4 : 0.f;  r5 = r5 > 0.f ? r5 : 0.f;
    r6 = r6 > 0.f ? r6 : 0.f;  r7 = r7 > 0.f ? r7 : 0.f;

    int q0 = __float2int_rn(fminf(r0 * qh, 32767.f));
    int q1 = __float2int_rn(fminf(r1 * qh, 32767.f));
    int q2 = __float2int_rn(fminf(r2 * qh, 32767.f));
    int q3 = __float2int_rn(fminf(r3 * qh, 32767.f));
    int q4 = __float2int_rn(fminf(r4 * qh, 32767.f));
    int q5 = __float2int_rn(fminf(r5 * qh, 32767.f));
    int q6 = __float2int_rn(fminf(r6 * qh, 32767.f));
    int q7 = __float2int_rn(fminf(r7 * qh, 32767.f));

    int4 pk;
    pk.x = (q0 & 0xffff) | (q1 << 16);
    pk.y = (q2 & 0xffff) | (q3 << 16);
    pk.z = (q4 & 0xffff) | (q5 << 16);
    pk.w = (q6 & 0xffff) | (q7 << 16);
    *((int4*)outq + (size_t)node * 8 + cl) = pk;
}

// fused sparse gather + prediction head: wave = 4 pairs; sub even=user, odd=movie
__global__ void __launch_bounds__(256) gather_final_kernel(
    const short* __restrict__ hsq, const int* __restrict__ row_ptr, const int* __restrict__ col,
    const int* __restrict__ users, const int* __restrict__ movies,
    const float* __restrict__ dinv, const float* __restrict__ b, float qinv,
    const float* __restrict__ fc_w, const float* __restrict__ fc_b,
    float* __restrict__ out, int batch) {
    const int4* __restrict__ hq4 = (const int4*)hsq;
    const int lane = threadIdx.x & 63;
    const int sub = lane >> 3;
    const int cl  = lane & 7;
    const int g = blockIdx.x * 4 + (threadIdx.x >> 6);

    int pair = g * 4 + (sub >> 1);
    int node = 0;   // dummy (valid memory) so all lanes participate in shuffles
    if (pair < batch) node = ((sub & 1) == 0) ? users[pair] : movies[pair];

    int acc[8];
    gather_node_q8(hq4, row_ptr, col, node, cl, acc);

    const float4* b4 = (const float4*)b;
    float4 bA = b4[cl * 2], bB = b4[cl * 2 + 1];
    float sq = dinv[node] * qinv;

    float r[8];
    r[0] = fmaf((float)acc[0], sq, bA.x);
    r[1] = fmaf((float)acc[1], sq, bA.y);
    r[2] = fmaf((float)acc[2], sq, bA.z);
    r[3] = fmaf((float)acc[3], sq, bA.w);
    r[4] = fmaf((float)acc[4], sq, bB.x);
    r[5] = fmaf((float)acc[5], sq, bB.y);
    r[6] = fmaf((float)acc[6], sq, bB.z);
    r[7] = fmaf((float)acc[7], sq, bB.w);
#pragma unroll
    for (int i = 0; i < 8; ++i) r[i] = r[i] > 0.f ? r[i] : 0.f;

    const float4* fw4 = (const float4*)fc_w;
    float4 fA = fw4[cl * 2], fB = fw4[cl * 2 + 1];
    float fw[8] = { fA.x, fA.y, fA.z, fA.w, fB.x, fB.y, fB.z, fB.w };

    // partner sub (u<->m) is lane ^ 8
    float s = 0.f;
#pragma unroll
    for (int i = 0; i < 8; ++i) {
        float p = __shfl_xor(r[i], 8, 64);
        s += r[i] * p * fw[i];
    }
    // reduce across the 8 cl lanes of this sub
#pragma unroll
    for (int off = 1; off < 8; off <<= 1)
        s += __shfl_xor(s, off, 64);

    // lanes 0,16,32,48 hold pairs g*4+0..3 (subs 0,2,4,6)
    if ((lane & 15) == 0) {
        int pr = g * 4 + (lane >> 4);
        if (pr < batch) out[pr] = s + fc_b[0];
    }
}

extern "C" void kernel_launch(void* const* d_in, const int* in_sizes, int n_in,
                              void* d_out, int out_size, void* d_ws, size_t ws_size,
                              hipStream_t stream) {
    const float* x     = (const float*)d_in[0];
    const int*   edge  = (const int*)d_in[1];   // [2][E]
    const int*   users = (const int*)d_in[2];
    const int*   movies= (const int*)d_in[3];
    const float* W1    = (const float*)d_in[4];
    const float* b1    = (const float*)d_in[5];
    const float* W2    = (const float*)d_in[6];
    const float* b2    = (const float*)d_in[7];
    const float* fc_w  = (const float*)d_in[8];
    const float* fc_b  = (const float*)d_in[9];
    float* out = (float*)d_out;

    const int IN_DIM = 128;
    const int n       = in_sizes[0] / IN_DIM;  // 100000
    const int n_edges = in_sizes[1] / 2;       // 1200000 (divisible by 4)
    const int batch   = in_sizes[2];           // 8192

    const int* esrc = edge;
    const int* edst = edge + n_edges;

    const int n4   = n_edges / 4;              // 300000
    const int NBLK = 512;                      // edge blocks for hist/partition
    const int EPB4 = (n4 + NBLK - 1) / NBLK;   // 586 int4 per block
    const int NB   = (n + 255) >> 8;           // 391 buckets
    const int HLEN = NB * NBLK;                // 200192
    const int SB   = (HLEN + 2047) / 2048;     // 98 scan blocks (<=128)

    char* ws = (char*)d_ws;
    size_t o = 0;
    auto alloc = [&](size_t bytes) { void* p = ws + o; o = (o + bytes + 255) & ~(size_t)255; return p; };
    int*   hist    = (int*)  alloc(sizeof(int) * HLEN);
    int*   tmp     = (int*)  alloc(sizeof(int) * HLEN);
    int*   bsum    = (int*)  alloc(sizeof(int) * 128);
    int*   sorted  = (int*)  alloc(sizeof(int) * n_edges);   // packed (src<<8)|(dst&255)
    int*   col     = (int*)  alloc(sizeof(int) * n_edges);
    int*   row_ptr = (int*)  alloc(sizeof(int) * (n + 1));
    float* dinv    = (float*)alloc(sizeof(float) * n);
    short* Bq      = (short*)alloc(sizeof(short) * (size_t)n * HID);  // q(hs1) then q(hs2)
    short* Hq      = (short*)alloc(sizeof(short) * (size_t)n * HID);  // q(h1)

    // ---- atomic-free CSR build + norm (4 dispatches) ----
    hist_kernel<<<NBLK, 256, 0, stream>>>((const int4*)edst, hist, n4, NBLK, NB, EPB4);
    scan_partial_kernel<<<SB, 1024, 0, stream>>>(hist, tmp, bsum, HLEN);
    partition_kernel<<<NBLK, 256, 0, stream>>>((const int4*)esrc, (const int4*)edst,
                                               tmp, bsum, sorted, n4, NBLK, NB, EPB4, SB);
    bucket_build_kernel<<<NB, 256, 0, stream>>>(sorted, tmp, bsum, row_ptr, dinv, col,
                                                NBLK, n, n_edges, SB);

    const int gemm_blocks = (n + 63) / 64;     // 1563 (~6.1 blocks/CU)
    const int gather_blocks = (n + 31) / 32;   // 8 nodes/wave, 4 waves/block -> 3125
    const int head_blocks = (batch + 15) / 16; // 4 pairs/wave, 4 waves/block -> 512

    // ---- layer 1 ----
    gemm_tile_kernel<128><<<gemm_blocks, 256, 0, stream>>>(x, W1, dinv, Bq, QS1, n);      // Bq = q(hs1)
    gather_kernel<<<gather_blocks, 256, 0, stream>>>(Bq, row_ptr, col, dinv, b1,
                                                     QINV1, QH1, Hq, n);                  // Hq = q(h1)

    // ---- layer 2 ----
    gemm_tile_q_kernel<<<gemm_blocks, 256, 0, stream>>>(Hq, W2, dinv, Bq, QS2 / QH1, n);  // Bq = q(hs2)
    gather_final_kernel<<<head_blocks, 256, 0, stream>>>(Bq, row_ptr, col, users, movies,
                                                         dinv, b2, QINV2, fc_w, fc_b,
                                                         out, batch);                     // out = scores
}